// Round 13
// baseline (383.272 us; speedup 1.0000x reference)
//
#include <hip/hip_runtime.h>
#include <hip/hip_bf16.h>

#define N_   8
#define P_   2048
#define K_   16
#define T1   8

typedef const float* fpp;
typedef __attribute__((ext_vector_type(8))) short short8;
typedef __attribute__((ext_vector_type(4))) short short4v;
typedef __attribute__((ext_vector_type(4))) float floatx4;

__device__ __forceinline__ float bcast(float v, int lane){
    return __uint_as_float(__builtin_amdgcn_readlane(__float_as_uint(v), (unsigned)lane));
}
__device__ __forceinline__ short f2bf(float f){
    unsigned u = __float_as_uint(f);
    unsigned r = (u + 0x7FFFu + ((u >> 16) & 1u)) >> 16;
    return (short)r;
}
__device__ __forceinline__ float bf2f(short s){
    return __uint_as_float(((unsigned)(unsigned short)s) << 16);
}
__device__ __forceinline__ float bf2fu(unsigned short s){
    return __uint_as_float(((unsigned)s) << 16);
}

// ------ pack points into float4 (x,y,z,|p|^2) once; L2-resident thereafter ------
__global__ __launch_bounds__(256) void pts_prep_kernel(fpp points, float4* pts4){
    const int i = blockIdx.x*256 + threadIdx.x;   // 16384 total
    const float x = points[i*3+0], y = points[i*3+1], z = points[i*3+2];
    pts4[i] = make_float4(x, y, z, x*x + y*y + z*z);
}

// ---- KNN v9 (proven: 59.9us, VALUBusy 60%): zero-LDS, instruction-dieted
//      insert machinery (readlane thr/dn, arithmetic qn, interleaved chains). ----
__global__ __launch_bounds__(256) void knn_kernel(const float4* pts4, int* idxo){
    const int t = threadIdx.x;
    const int wave = t >> 6, lane = t & 63;
    const int n  = blockIdx.x >> 8;           // 256 blocks per batch
    const int p0 = (blockIdx.x & 255) * 8;
    const int base = n << 11;
    const float4* cand = pts4 + base;
    const int plb = p0 + wave*2;
    float px[2], py[2], pz[2], rp[2];
    #pragma unroll
    for (int i=0;i<2;i++){
        const float4 me = cand[plb + i];
        px[i]=me.x; py[i]=me.y; pz[i]=me.z; rp[i]=me.w;
    }
    float sd[2]; int sq[2];
    {
        const float4 c = cand[lane];
        #pragma unroll
        for (int i=0;i<2;i++){
            sd[i] = (rp[i] - 2.0f*(px[i]*c.x + py[i]*c.y + pz[i]*c.z)) + c.w;
            sq[i] = lane;
        }
        #pragma unroll
        for (int k = 2; k <= 64; k <<= 1){
            #pragma unroll
            for (int j = k >> 1; j > 0; j >>= 1){
                const bool takeSmaller = ((lane & k) == 0) == ((lane & j) == 0);
                #pragma unroll
                for (int i=0;i<2;i++){
                    const float od = __shfl_xor(sd[i], j);
                    const int   oi = __shfl_xor(sq[i], j);
                    const bool otherLess = (od < sd[i]) || (od == sd[i] && oi < sq[i]);
                    const bool take = (takeSmaller == otherLess);
                    sd[i] = take ? od : sd[i];
                    sq[i] = take ? oi : sq[i];
                }
            }
        }
    }
    for (int s = 1; s < 32; ++s){
        const int ci0 = s*64;
        const float4 c = cand[ci0 + lane];
        float d[2]; unsigned long long mask[2];
        #pragma unroll
        for (int i=0;i<2;i++)
            d[i] = (rp[i] - 2.0f*(px[i]*c.x + py[i]*c.y + pz[i]*c.z)) + c.w;
        #pragma unroll
        for (int i=0;i<2;i++){
            const float thr = bcast(sd[i], 16);          // readlane, SALU
            mask[i] = __ballot(d[i] < thr);
        }
        // interleaved insert loops: the two serial shfl_up chains overlap
        while (mask[0] | mask[1]){
            #pragma unroll
            for (int i=0;i<2;i++){
                if (mask[i]){
                    const int src = __ffsll((long long)mask[i]) - 1;
                    mask[i] &= mask[i] - 1;
                    const float dn = bcast(d[i], src);   // readlane, uniform src
                    const int   qn = ci0 + src;          // pure arithmetic
                    float shd = __shfl_up(sd[i], 1);
                    int   shq = __shfl_up(sq[i], 1);
                    if (lane == 0) shd = -__builtin_inff();
                    const bool c1 = shd > dn;
                    const bool c2 = sd[i] > dn;
                    sq[i] = c1 ? shq : (c2 ? qn : sq[i]);
                    sd[i] = c1 ? shd : (c2 ? dn : sd[i]);
                }
            }
        }
    }
    if (lane >= 1 && lane <= 16){
        #pragma unroll
        for (int i=0;i<2;i++)
            idxo[(base + plb + i)*K_ + (lane - 1)] = base + sq[i];
    }
}

// ------ per-point transforms v2: 5 waves (320 thr).
//        w0: U, w1: V, w2: AU/AV, w3-4: SC stats (sc_stats kernel folded in). ------
__global__ __launch_bounds__(320) void feat_gemm_kernel(fpp feat, fpp w0, fpp aw1, fpp scw,
        float* U, float* V, float* AU, float* AV, float* scs, float* scq){
    const int t = threadIdx.x;
    const int w = t >> 6, lane = t & 63;
    const int row0 = blockIdx.x * 16;
    float wreg[64];
    if (w == 0){
        #pragma unroll
        for (int c=0;c<64;c++) wreg[c] = w0[lane*128+c] - w0[lane*128+64+c];
    } else if (w == 1){
        #pragma unroll
        for (int c=0;c<64;c++) wreg[c] = w0[lane*128+64+c];
    } else if (w == 2){
        if (lane < 32){
            #pragma unroll
            for (int c=0;c<64;c++) wreg[c] = aw1[lane*128+c] - aw1[lane*128+64+c];
        } else {
            const int o = lane - 32;
            #pragma unroll
            for (int c=0;c<64;c++) wreg[c] = aw1[o*128+64+c];
        }
    } else {
        const int o = (w-3)*64 + lane;
        #pragma unroll
        for (int c=0;c<64;c++) wreg[c] = scw[o*64+c];
    }
    float psum=0.f, psq=0.f;
    for (int r=0;r<16;r++){
        const int row = row0 + r;
        const float fv = feat[row*64 + lane];
        float acc = 0.f;
        #pragma unroll
        for (int c=0;c<64;c++) acc = fmaf(bcast(fv, c), wreg[c], acc);
        if      (w==0) U[row*64+lane]=acc;
        else if (w==1) V[row*64+lane]=acc;
        else if (w==2){ if (lane<32) AU[row*32+lane]=acc; else AV[row*32+lane-32]=acc; }
        else { psum += acc; psq += acc*acc; }
    }
    if (w >= 3){
        const int o = (w-3)*64 + lane;
        atomicAdd(&scs[o], psum);
        atomicAdd(&scq[o], psq);
    }
}

// ------ attention + BN0 stats v2: 2048 blocks x 2 pts/wave (was 512 x 8).
//        Grid was the occupancy cap: 512 blocks = 8 waves/CU = 25%.
//        Now 8 blocks/CU = 32 waves/CU for a latency-heavy gather kernel. ------
__global__ __launch_bounds__(256) void attn_bn0_kernel(const int* idx, const float* U, const float* V,
        const float* AU, const float* AV, fpp b1, fpp w2, fpp b2, fpp tau,
        float* attw, float* bn0s, float* bn0q){
    __shared__ float sAV[4][16][36];
    const int t = threadIdx.x, w = t>>6, lane = t&63;
    const int pt0 = blockIdx.x*8 + w*2;
    const int kk = lane >> 2, h = lane & 3;
    float w2r[32];
    #pragma unroll
    for (int c=0;c<32;c++) w2r[c] = w2[h*32+c];
    const float b2v = b2[h];
    const float tv  = tau[0];
    float ssum=0.f, ssq=0.f;
    for (int j=0;j<2;j++){
        const int pt = pt0 + j;
        const int* ip = idx + pt*K_;
        {
            const int fl = lane >> 2, part = lane & 3;
            const int qf = ip[fl];
            const float4 a = *(const float4*)&AV[qf*32 + part*8];
            const float4 b = *(const float4*)&AV[qf*32 + part*8 + 4];
            *(float4*)&sAV[w][fl][part*8]     = a;
            *(float4*)&sAV[w][fl][part*8 + 4] = b;
        }
        __builtin_amdgcn_wave_barrier();
        const float uv = U[pt*64+lane];
        for (int k=0;k<K_;k++){
            const int q = ip[k];
            const float v = uv + V[q*64+lane];
            ssum += v; ssq += v*v;
        }
        float a2 = b2v;
        for (int c=0;c<32;c++){
            float a1 = AU[pt*32+c] + sAV[w][kk][c] + b1[c];
            a1 = a1 > 0.f ? a1 : 0.2f*a1;
            a2 = fmaf(a1, w2r[c], a2);
        }
        const float lt = a2 / tv;
        float m = lt;
        m = fmaxf(m, __shfl_xor(m, 4));  m = fmaxf(m, __shfl_xor(m, 8));
        m = fmaxf(m, __shfl_xor(m, 16)); m = fmaxf(m, __shfl_xor(m, 32));
        const float e = expf(lt - m);
        float s = e;
        s += __shfl_xor(s, 4);  s += __shfl_xor(s, 8);
        s += __shfl_xor(s, 16); s += __shfl_xor(s, 32);
        attw[pt*64 + lane] = e / s;
        __builtin_amdgcn_wave_barrier();
    }
    __shared__ float rs[256], rq[256];
    rs[t]=ssum; rq[t]=ssq; __syncthreads();
    if (t < 64){
        atomicAdd(&bn0s[t], rs[t]+rs[t+64]+rs[t+128]+rs[t+192]);
        atomicAdd(&bn0q[t], rq[t]+rq[t+64]+rq[t+128]+rq[t+192]);
    }
}

// ------ fold BN into per-channel scale/shift ------
__global__ __launch_bounds__(128) void bn_finalize_kernel(const float* s, const float* q, fpp g, fpp b,
        float inv_cnt, int C, float* scale, float* shift){
    const int c = threadIdx.x;
    if (c < C){
        const float mu  = s[c]*inv_cnt;
        const float var = fmaxf(q[c]*inv_cnt - mu*mu, 0.f);
        const float sc  = g[c] * rsqrtf(var + 1e-5f);
        scale[c]=sc; shift[c] = b[c] - mu*sc;
    }
}

// ------ merged BN0 + SC finalize ------
__global__ __launch_bounds__(192) void bn_finalize2_kernel(const float* s0, const float* q0,
        fpp g0, fpp b0, const float* ss, const float* qs, fpp gs, fpp bs,
        float* sc0, float* sh0, float* scsc, float* shsc){
    const int c = threadIdx.x;
    if (c < 64){
        const float mu  = s0[c]*(1.0f/262144.0f);
        const float var = fmaxf(q0[c]*(1.0f/262144.0f) - mu*mu, 0.f);
        const float sc  = g0[c] * rsqrtf(var + 1e-5f);
        sc0[c]=sc; sh0[c]=b0[c]-mu*sc;
    } else {
        const int cc = c - 64;
        const float mu  = ss[cc]*(1.0f/16384.0f);
        const float var = fmaxf(qs[cc]*(1.0f/16384.0f) - mu*mu, 0.f);
        const float sc  = gs[cc] * rsqrtf(var + 1e-5f);
        scsc[cc]=sc; shsc[cc]=bs[cc]-mu*sc;
    }
}

// ====== MFMA conv1 v2: 512 threads (8 waves), wave = (M-tile, N-half).
//        LDS 37KB -> 4 blocks/CU x 8 waves = 32 waves/CU. ======
__global__ __launch_bounds__(512) void mfma_conv1_kernel(const int* idx, const float* U, const float* V,
        fpp w1, const float* sc0, const float* sh0, float* bn1s, float* bn1q,
        unsigned short* y1out){
    __shared__ __align__(16) short WH[64*72], WL[64*72];
    __shared__ __align__(16) short AH[64*72], AL[64*72];
    __shared__ float ssum[64], ssq[64];
    const int t = threadIdx.x, lane = t & 63, w = t >> 6;
    const int L = lane & 15, Q = lane >> 4;
    for (int i = t; i < 4096; i += 512){
        const float wv = w1[i];
        const short hh = f2bf(wv);
        const int n = i >> 6, k = i & 63;
        WH[n*72+k] = hh;
        WL[n*72+k] = f2bf(wv - bf2f(hh));
    }
    if (t < 64){ ssum[t]=0.f; ssq[t]=0.f; }
    __syncthreads();
    const int nbase = (w >> 2) * 2;          // N-half: tiles {0,1} or {2,3}
    short8 bh[2][2], bl[2][2];
    #pragma unroll
    for (int nt=0; nt<2; ++nt){
        #pragma unroll
        for (int ks=0; ks<2; ++ks){
            const int off = ((nbase+nt)*16+L)*72 + ks*32 + Q*8;
            bh[nt][ks] = *(const short8*)&WH[off];
            bl[nt][ks] = *(const short8*)&WL[off];
        }
    }
    const int m0 = (w & 3) * 16;
    const int r = t >> 3, c8 = (t & 7) * 8;  // staging: edge r, 8 channels
    float sacc[2] = {0,0}, qacc[2] = {0,0};
    for (int tile = 0; tile < T1; ++tile){
        __syncthreads();
        const int e0 = (blockIdx.x*T1 + tile) * 64;
        {
            const int s = e0 + r;
            const int p = s >> 4, q = idx[s];
            const float4* up = (const float4*)&U[p*64 + c8];
            const float4* vq = (const float4*)&V[q*64 + c8];
            #pragma unroll
            for (int b4=0; b4<2; ++b4){
                const float4 uv4 = up[b4];
                const float4 vv4 = vq[b4];
                const int c0 = c8 + b4*4;
                float av[4] = {uv4.x+vv4.x, uv4.y+vv4.y, uv4.z+vv4.z, uv4.w+vv4.w};
                short4v h4, l4;
                #pragma unroll
                for (int j=0;j<4;j++){
                    const int c = c0 + j;
                    const float a0 = fmaxf(fmaf(av[j], sc0[c], sh0[c]), 0.f);
                    const short hh = f2bf(a0);
                    h4[j] = hh;
                    l4[j] = f2bf(a0 - bf2f(hh));
                }
                *(short4v*)&AH[r*72 + c0] = h4;
                *(short4v*)&AL[r*72 + c0] = l4;
            }
        }
        __syncthreads();
        floatx4 acc[2];
        #pragma unroll
        for (int nt=0;nt<2;nt++) acc[nt] = (floatx4){0.f,0.f,0.f,0.f};
        #pragma unroll
        for (int ks=0; ks<2; ++ks){
            const int aoff = (m0 + L)*72 + ks*32 + Q*8;
            const short8 ah = *(const short8*)&AH[aoff];
            const short8 al = *(const short8*)&AL[aoff];
            #pragma unroll
            for (int nt=0;nt<2;nt++){
                acc[nt] = __builtin_amdgcn_mfma_f32_16x16x32_bf16(ah, bh[nt][ks], acc[nt], 0,0,0);
                acc[nt] = __builtin_amdgcn_mfma_f32_16x16x32_bf16(ah, bl[nt][ks], acc[nt], 0,0,0);
                acc[nt] = __builtin_amdgcn_mfma_f32_16x16x32_bf16(al, bh[nt][ks], acc[nt], 0,0,0);
            }
        }
        #pragma unroll
        for (int nt=0;nt<2;nt++){
            const int o = (nbase+nt)*16 + L;
            #pragma unroll
            for (int rr=0;rr<4;rr++){
                const float v = acc[nt][rr];
                y1out[(e0 + m0 + Q*4 + rr)*64 + o] = (unsigned short)f2bf(v);
                sacc[nt]+=v; qacc[nt]+=v*v;
            }
        }
    }
    #pragma unroll
    for (int nt=0;nt<2;nt++){
        atomicAdd(&ssum[(nbase+nt)*16+L], sacc[nt]);
        atomicAdd(&ssq [(nbase+nt)*16+L], qacc[nt]);
    }
    __syncthreads();
    if (t < 64){
        atomicAdd(&bn1s[t], ssum[t]);
        atomicAdd(&bn1q[t], ssq[t]);
    }
}

// ====== MFMA conv2 v4: 512 threads (8 waves), wave = (M-tile, N-half of 8 tiles).
//        LDS 56KB -> 2 blocks/CU x 8 waves = 16 waves/CU. ======
__global__ __launch_bounds__(512) void mfma_conv2_kernel(const unsigned short* y1in,
        fpp w2, const float* sc1, const float* sh1,
        float* bn2s, float* bn2q, unsigned short* y2out){
    __shared__ __align__(16) short WH2[128*72], WL2[128*72];
    __shared__ __align__(16) short AH[64*72], AL[64*72];
    __shared__ float ssum[128], ssq[128];
    const int t = threadIdx.x, lane = t & 63, w = t >> 6;
    const int L = lane & 15, Q = lane >> 4;
    for (int i = t; i < 8192; i += 512){
        const float wv = w2[i];
        const short hh = f2bf(wv);
        WH2[(i>>6)*72+(i&63)] = hh;
        WL2[(i>>6)*72+(i&63)] = f2bf(wv - bf2f(hh));
    }
    if (t < 128){ ssum[t]=0.f; ssq[t]=0.f; }
    const int nbase = (w >> 2) * 4;          // N-half: tiles {0..3} or {4..7}
    const int m0 = (w & 3) * 16;
    const int r = t >> 3, c8 = (t & 7) * 8;  // staging: edge r, 8 channels
    float s1r[8], h1r[8];
    #pragma unroll
    for (int j=0;j<8;j++){ s1r[j] = sc1[c8+j]; h1r[j] = sh1[c8+j]; }
    float sacc[4] = {0,0,0,0}, qacc[4] = {0,0,0,0};
    for (int tile = 0; tile < T1; ++tile){
        __syncthreads();
        const int e0 = (blockIdx.x*T1 + tile) * 64;
        {
            const short8 y8 = *(const short8*)&y1in[(e0 + r)*64 + c8];
            short4v h4, l4;
            #pragma unroll
            for (int g=0; g<2; ++g){
                #pragma unroll
                for (int j=0;j<4;j++){
                    const int jj = g*4 + j;
                    const float a1 = fmaxf(fmaf(bf2fu((unsigned short)y8[jj]),
                                                s1r[jj], h1r[jj]), 0.f);
                    const short hh = f2bf(a1);
                    h4[j] = hh;
                    l4[j] = f2bf(a1 - bf2f(hh));
                }
                const int c0 = c8 + g*4;
                *(short4v*)&AH[r*72 + c0] = h4;
                *(short4v*)&AL[r*72 + c0] = l4;
            }
        }
        __syncthreads();
        floatx4 acc2[4];
        #pragma unroll
        for (int nt=0;nt<4;nt++) acc2[nt] = (floatx4){0.f,0.f,0.f,0.f};
        #pragma unroll
        for (int ks=0; ks<2; ++ks){
            const int aoff = (m0 + L)*72 + ks*32 + Q*8;
            const short8 ah = *(const short8*)&AH[aoff];
            const short8 al = *(const short8*)&AL[aoff];
            #pragma unroll
            for (int nt=0;nt<4;nt++){
                const int boff = ((nbase+nt)*16+L)*72 + ks*32 + Q*8;
                const short8 wh = *(const short8*)&WH2[boff];
                const short8 wl = *(const short8*)&WL2[boff];
                acc2[nt] = __builtin_amdgcn_mfma_f32_16x16x32_bf16(ah, wh, acc2[nt], 0,0,0);
                acc2[nt] = __builtin_amdgcn_mfma_f32_16x16x32_bf16(ah, wl, acc2[nt], 0,0,0);
                acc2[nt] = __builtin_amdgcn_mfma_f32_16x16x32_bf16(al, wh, acc2[nt], 0,0,0);
            }
        }
        #pragma unroll
        for (int nt=0;nt<4;nt++){
            const int o = (nbase+nt)*16 + L;
            #pragma unroll
            for (int rr=0;rr<4;rr++){
                const float v = acc2[nt][rr];
                const int s = e0 + m0 + Q*4 + rr;
                y2out[s*128 + o] = (unsigned short)f2bf(v);
                sacc[nt] += v; qacc[nt] += v*v;
            }
        }
    }
    #pragma unroll
    for (int nt=0;nt<4;nt++){
        atomicAdd(&ssum[(nbase+nt)*16+L], sacc[nt]);
        atomicAdd(&ssq [(nbase+nt)*16+L], qacc[nt]);
    }
    __syncthreads();
    if (t < 128){
        atomicAdd(&bn2s[t], ssum[t]);
        atomicAdd(&bn2q[t], ssq[t]);
    }
}

// ------ combine v2: channel-pair per lane -> uint loads (4B/lane, coalesced),
//        one shared attw read per pair, float2 stores. Math identical. ------
__global__ __launch_bounds__(256) void combine_fast_kernel(const unsigned short* y2, const float* attw,
        const float* sc2, const float* sh2, float* xcomb, float* msum){
    __shared__ float rs[512];
    const int t=threadIdx.x, w=t>>6, lane=t&63;
    const int c0 = lane*2;
    const float s2a=sc2[c0], h2a=sh2[c0], s2b=sc2[c0+1], h2b=sh2[c0+1];
    const int pt0 = blockIdx.x*16 + w*4;
    const int hsel = lane >> 4;              // = c0>>5, same head for both channels
    float m0=0.f, m1=0.f;
    for (int j=0;j<4;j++){
        const int pt = pt0 + j;
        float acc0=0.f, acc1=0.f;
        for (int k=0;k<K_;k++){
            const int s = pt*K_ + k;
            const unsigned v = *(const unsigned*)&y2[s*128 + c0];
            const float aw = attw[s*4 + hsel];
            const float r0 = fmaxf(fmaf(bf2fu((unsigned short)(v & 0xFFFFu)), s2a, h2a), 0.f);
            const float r1 = fmaxf(fmaf(bf2fu((unsigned short)(v >> 16)),    s2b, h2b), 0.f);
            acc0 = fmaf(r0, aw, acc0);
            acc1 = fmaf(r1, aw, acc1);
        }
        *(float2*)&xcomb[pt*128 + c0] = make_float2(acc0, acc1);
        m0 += acc0; m1 += acc1;
    }
    rs[t]=m0; rs[256+t]=m1; __syncthreads();
    if (t<64){
        const int n = (blockIdx.x*16) >> 11;
        atomicAdd(&msum[n*128+2*t],   rs[t]+rs[t+64]+rs[t+128]+rs[t+192]);
        atomicAdd(&msum[n*128+2*t+1], rs[256+t]+rs[256+t+64]+rs[256+t+128]+rs[256+t+192]);
    }
}

// ------ final v3: SE gate fused in (se_kernel eliminated). 256 thr:
//        2 row-groups x 128 ch. Each block recomputes the tiny SE MLP
//        (~8K fma, redundant, negligible) for its (uniform) batch. ------
__global__ __launch_bounds__(256) void final_kernel(fpp feat, fpp scw, const float* xcomb,
        const float* msum, fpp w1se, fpp w2se,
        const float* scsc, const float* shsc, float* out){
    __shared__ float swc[128*65];
    __shared__ float sf[16*64];
    __shared__ float tl[32];
    const int t = threadIdx.x;
    for (int i=t;i<8192;i+=256) swc[(i>>6)*65+(i&63)] = scw[i];
    const int row0 = blockIdx.x*16;
    const int n = row0 >> 11;                // uniform: 2048 % 16 == 0
    for (int i=t;i<1024;i+=256) sf[i] = feat[row0*64+i];
    if (t < 32){
        float acc=0.f;
        for (int c=0;c<128;c++) acc = fmaf(msum[n*128+c]*(1.f/2048.f), w1se[t*128+c], acc);
        tl[t] = fmaxf(acc, 0.f);
    }
    __syncthreads();
    const int c = t & 127, rg = t >> 7;
    float acc2 = 0.f;
    for (int hh=0;hh<32;hh++) acc2 = fmaf(tl[hh], w2se[c*32+hh], acc2);
    const float sev = 1.f/(1.f+expf(-acc2));
    const float scl = scsc[c], shf = shsc[c];
    for (int r=rg*8; r<rg*8+8; r++){
        const int row = row0 + r;
        float acc = 0.f;
        #pragma unroll
        for (int k=0;k<64;k++) acc = fmaf(sf[r*64+k], swc[c*65+k], acc);
        out[row*128+c] = xcomb[row*128+c]*sev + fmaxf(fmaf(acc, scl, shf), 0.f);
    }
}

extern "C" void kernel_launch(void* const* d_in, const int* in_sizes, int n_in,
                              void* d_out, int out_size, void* d_ws, size_t ws_size,
                              hipStream_t stream) {
    fpp points  = (fpp)d_in[0];
    fpp feat    = (fpp)d_in[1];
    fpp conv_w0 = (fpp)d_in[2];
    fpp conv_w1 = (fpp)d_in[3];
    fpp conv_w2 = (fpp)d_in[4];
    fpp bn_g0 = (fpp)d_in[5],  bn_b0 = (fpp)d_in[6];
    fpp bn_g1 = (fpp)d_in[7],  bn_b1 = (fpp)d_in[8];
    fpp bn_g2 = (fpp)d_in[9],  bn_b2 = (fpp)d_in[10];
    fpp attn_w1 = (fpp)d_in[11], attn_b1 = (fpp)d_in[12];
    fpp attn_w2 = (fpp)d_in[13], attn_b2 = (fpp)d_in[14];
    fpp tau  = (fpp)d_in[15];
    fpp sc_w = (fpp)d_in[16], sc_g = (fpp)d_in[17], sc_b = (fpp)d_in[18];
    fpp se_w1 = (fpp)d_in[19], se_w2 = (fpp)d_in[20];

    float* W = (float*)d_ws;
    float* BN0S=W+0;    float* BN0Q=W+64;
    float* BN1S=W+128;  float* BN1Q=W+192;
    float* BN2S=W+256;  float* BN2Q=W+384;
    float* SCS =W+512;  float* SCQ =W+640;
    float* SC0 =W+768;  float* SH0 =W+832;
    float* SC1 =W+896;  float* SH1 =W+960;
    float* SC2 =W+1024; float* SH2 =W+1152;
    float* SCSC=W+1280; float* SHSC=W+1408;
    float* MSUM=W+1536; float* SEV =W+2560;
    int*   IDX  = (int*)(W + 4096);
    float* U    = W + 266240;
    float* V    = U + 1048576;
    float* AU   = V + 1048576;
    float* AV   = AU + 524288;
    float* ATTW = AV + 524288;
    float* XCOMB= ATTW + 1048576;                          // ends 6,557,696 floats
    unsigned short* Y2 = (unsigned short*)(W + 6557696);   // 33,554,432 ushort
    unsigned short* Y1 = Y2 + 33554432;                    // 16,777,216 ushort
    // PTS4 aliases XCOMB (knn finishes long before combine writes XCOMB)
    float4* PTS4 = (float4*)XCOMB;                         // 16384 float4 = 256 KB

    hipMemsetAsync(d_ws, 0, 4096*sizeof(float), stream);

    pts_prep_kernel<<<64, 256, 0, stream>>>(points, PTS4);
    knn_kernel<<<2048, 256, 0, stream>>>(PTS4, IDX);
    feat_gemm_kernel<<<1024, 320, 0, stream>>>(feat, conv_w0, attn_w1, sc_w,
                                               U, V, AU, AV, SCS, SCQ);
    attn_bn0_kernel<<<2048, 256, 0, stream>>>(IDX, U, V, AU, AV,
                                              attn_b1, attn_w2, attn_b2, tau,
                                              ATTW, BN0S, BN0Q);
    bn_finalize2_kernel<<<1, 192, 0, stream>>>(BN0S, BN0Q, bn_g0, bn_b0,
                                               SCS, SCQ, sc_g, sc_b,
                                               SC0, SH0, SCSC, SHSC);
    mfma_conv1_kernel<<<512, 512, 0, stream>>>(IDX, U, V, conv_w1, SC0, SH0,
                                               BN1S, BN1Q, Y1);
    bn_finalize_kernel<<<1, 128, 0, stream>>>(BN1S, BN1Q, bn_g1, bn_b1,
                                              1.0f/262144.0f, 64, SC1, SH1);
    mfma_conv2_kernel<<<512, 512, 0, stream>>>(Y1, conv_w2, SC1, SH1,
                                               BN2S, BN2Q, Y2);
    bn_finalize_kernel<<<1, 128, 0, stream>>>(BN2S, BN2Q, bn_g2, bn_b2,
                                              1.0f/262144.0f, 128, SC2, SH2);
    combine_fast_kernel<<<1024, 256, 0, stream>>>(Y2, ATTW, SC2, SH2, XCOMB, MSUM);
    final_kernel<<<1024, 256, 0, stream>>>(feat, sc_w, XCOMB, MSUM, se_w1, se_w2,
                                           SCSC, SHSC, (float*)d_out);
}

// Round 14
// 382.516 us; speedup vs baseline: 1.0020x; 1.0020x over previous
//
#include <hip/hip_runtime.h>
#include <hip/hip_bf16.h>

#define N_   8
#define P_   2048
#define K_   16
#define T1   8

typedef const float* fpp;
typedef __attribute__((ext_vector_type(8))) short short8;
typedef __attribute__((ext_vector_type(4))) short short4v;
typedef __attribute__((ext_vector_type(4))) float floatx4;

__device__ __forceinline__ float bcast(float v, int lane){
    return __uint_as_float(__builtin_amdgcn_readlane(__float_as_uint(v), (unsigned)lane));
}
__device__ __forceinline__ short f2bf(float f){
    unsigned u = __float_as_uint(f);
    unsigned r = (u + 0x7FFFu + ((u >> 16) & 1u)) >> 16;
    return (short)r;
}
__device__ __forceinline__ float bf2f(short s){
    return __uint_as_float(((unsigned)(unsigned short)s) << 16);
}
__device__ __forceinline__ float bf2fu(unsigned short s){
    return __uint_as_float(((unsigned)s) << 16);
}

// ------ pack points into float4 (x,y,z,|p|^2) once; L2-resident thereafter ------
__global__ __launch_bounds__(256) void pts_prep_kernel(fpp points, float4* pts4){
    const int i = blockIdx.x*256 + threadIdx.x;   // 16384 total
    const float x = points[i*3+0], y = points[i*3+1], z = points[i*3+2];
    pts4[i] = make_float4(x, y, z, x*x + y*y + z*z);
}

// ---- KNN v9 (proven: 59.9us, VALUBusy 60%): zero-LDS, instruction-dieted
//      insert machinery (readlane thr/dn, arithmetic qn, interleaved chains). ----
__global__ __launch_bounds__(256) void knn_kernel(const float4* pts4, int* idxo){
    const int t = threadIdx.x;
    const int wave = t >> 6, lane = t & 63;
    const int n  = blockIdx.x >> 8;           // 256 blocks per batch
    const int p0 = (blockIdx.x & 255) * 8;
    const int base = n << 11;
    const float4* cand = pts4 + base;
    const int plb = p0 + wave*2;
    float px[2], py[2], pz[2], rp[2];
    #pragma unroll
    for (int i=0;i<2;i++){
        const float4 me = cand[plb + i];
        px[i]=me.x; py[i]=me.y; pz[i]=me.z; rp[i]=me.w;
    }
    float sd[2]; int sq[2];
    {
        const float4 c = cand[lane];
        #pragma unroll
        for (int i=0;i<2;i++){
            sd[i] = (rp[i] - 2.0f*(px[i]*c.x + py[i]*c.y + pz[i]*c.z)) + c.w;
            sq[i] = lane;
        }
        #pragma unroll
        for (int k = 2; k <= 64; k <<= 1){
            #pragma unroll
            for (int j = k >> 1; j > 0; j >>= 1){
                const bool takeSmaller = ((lane & k) == 0) == ((lane & j) == 0);
                #pragma unroll
                for (int i=0;i<2;i++){
                    const float od = __shfl_xor(sd[i], j);
                    const int   oi = __shfl_xor(sq[i], j);
                    const bool otherLess = (od < sd[i]) || (od == sd[i] && oi < sq[i]);
                    const bool take = (takeSmaller == otherLess);
                    sd[i] = take ? od : sd[i];
                    sq[i] = take ? oi : sq[i];
                }
            }
        }
    }
    for (int s = 1; s < 32; ++s){
        const int ci0 = s*64;
        const float4 c = cand[ci0 + lane];
        float d[2]; unsigned long long mask[2];
        #pragma unroll
        for (int i=0;i<2;i++)
            d[i] = (rp[i] - 2.0f*(px[i]*c.x + py[i]*c.y + pz[i]*c.z)) + c.w;
        #pragma unroll
        for (int i=0;i<2;i++){
            const float thr = bcast(sd[i], 16);          // readlane, SALU
            mask[i] = __ballot(d[i] < thr);
        }
        // interleaved insert loops: the two serial shfl_up chains overlap
        while (mask[0] | mask[1]){
            #pragma unroll
            for (int i=0;i<2;i++){
                if (mask[i]){
                    const int src = __ffsll((long long)mask[i]) - 1;
                    mask[i] &= mask[i] - 1;
                    const float dn = bcast(d[i], src);   // readlane, uniform src
                    const int   qn = ci0 + src;          // pure arithmetic
                    float shd = __shfl_up(sd[i], 1);
                    int   shq = __shfl_up(sq[i], 1);
                    if (lane == 0) shd = -__builtin_inff();
                    const bool c1 = shd > dn;
                    const bool c2 = sd[i] > dn;
                    sq[i] = c1 ? shq : (c2 ? qn : sq[i]);
                    sd[i] = c1 ? shd : (c2 ? dn : sd[i]);
                }
            }
        }
    }
    if (lane >= 1 && lane <= 16){
        #pragma unroll
        for (int i=0;i<2;i++)
            idxo[(base + plb + i)*K_ + (lane - 1)] = base + sq[i];
    }
}

// ------ per-point transforms v2: 5 waves (320 thr).
//        w0: U, w1: V, w2: AU/AV, w3-4: SC stats (sc_stats kernel folded in). ------
__global__ __launch_bounds__(320) void feat_gemm_kernel(fpp feat, fpp w0, fpp aw1, fpp scw,
        float* U, float* V, float* AU, float* AV, float* scs, float* scq){
    const int t = threadIdx.x;
    const int w = t >> 6, lane = t & 63;
    const int row0 = blockIdx.x * 16;
    float wreg[64];
    if (w == 0){
        #pragma unroll
        for (int c=0;c<64;c++) wreg[c] = w0[lane*128+c] - w0[lane*128+64+c];
    } else if (w == 1){
        #pragma unroll
        for (int c=0;c<64;c++) wreg[c] = w0[lane*128+64+c];
    } else if (w == 2){
        if (lane < 32){
            #pragma unroll
            for (int c=0;c<64;c++) wreg[c] = aw1[lane*128+c] - aw1[lane*128+64+c];
        } else {
            const int o = lane - 32;
            #pragma unroll
            for (int c=0;c<64;c++) wreg[c] = aw1[o*128+64+c];
        }
    } else {
        const int o = (w-3)*64 + lane;
        #pragma unroll
        for (int c=0;c<64;c++) wreg[c] = scw[o*64+c];
    }
    float psum=0.f, psq=0.f;
    for (int r=0;r<16;r++){
        const int row = row0 + r;
        const float fv = feat[row*64 + lane];
        float acc = 0.f;
        #pragma unroll
        for (int c=0;c<64;c++) acc = fmaf(bcast(fv, c), wreg[c], acc);
        if      (w==0) U[row*64+lane]=acc;
        else if (w==1) V[row*64+lane]=acc;
        else if (w==2){ if (lane<32) AU[row*32+lane]=acc; else AV[row*32+lane-32]=acc; }
        else { psum += acc; psq += acc*acc; }
    }
    if (w >= 3){
        const int o = (w-3)*64 + lane;
        atomicAdd(&scs[o], psum);
        atomicAdd(&scq[o], psq);
    }
}

// ------ attention + BN0 stats v3: 2 points per wave processed CONCURRENTLY
//        (knn-v9 ILP recipe): both AV tiles staged up-front (one fence),
//        both V-gather streams in flight (32 loads), both 32-step a2 chains
//        overlap (2x ILP on the 4-cy fmaf dep), softmaxes interleaved.
//        LDS [4][2][16][36] + red = 20480B -> exactly 8 blocks/CU. ------
__global__ __launch_bounds__(256) void attn_bn0_kernel(const int* idx, const float* U, const float* V,
        const float* AU, const float* AV, fpp b1, fpp w2, fpp b2, fpp tau,
        float* attw, float* bn0s, float* bn0q){
    __shared__ float sAV[4][2][16][36];
    __shared__ float rs[256], rq[256];
    const int t = threadIdx.x, w = t>>6, lane = t&63;
    const int pt0 = blockIdx.x*8 + w*2;
    const int kk = lane >> 2, h = lane & 3;
    float w2r[32];
    #pragma unroll
    for (int c=0;c<32;c++) w2r[c] = w2[h*32+c];
    const float b2v = b2[h];
    const float tv  = tau[0];
    const int* ip0 = idx + pt0*K_;
    const int* ip1 = idx + (pt0+1)*K_;
    // stage both points' AV tiles (8 independent float4 loads), one fence
    {
        const int fl = lane >> 2, part = lane & 3;
        const int qf0 = ip0[fl], qf1 = ip1[fl];
        const float4 a0 = *(const float4*)&AV[qf0*32 + part*8];
        const float4 a1 = *(const float4*)&AV[qf0*32 + part*8 + 4];
        const float4 b0 = *(const float4*)&AV[qf1*32 + part*8];
        const float4 b1v= *(const float4*)&AV[qf1*32 + part*8 + 4];
        *(float4*)&sAV[w][0][fl][part*8]     = a0;
        *(float4*)&sAV[w][0][fl][part*8 + 4] = a1;
        *(float4*)&sAV[w][1][fl][part*8]     = b0;
        *(float4*)&sAV[w][1][fl][part*8 + 4] = b1v;
    }
    __builtin_amdgcn_wave_barrier();
    const float uv0 = U[pt0*64+lane];
    const float uv1 = U[(pt0+1)*64+lane];
    float ssum=0.f, ssq=0.f;
    for (int k=0;k<K_;k++){
        const int q0 = ip0[k], q1 = ip1[k];
        const float v0 = uv0 + V[q0*64+lane];
        const float v1 = uv1 + V[q1*64+lane];
        ssum += v0 + v1; ssq += v0*v0 + v1*v1;
    }
    float a2_0 = b2v, a2_1 = b2v;
    for (int c=0;c<32;c++){
        float x0 = AU[pt0*32+c]     + sAV[w][0][kk][c] + b1[c];
        float x1 = AU[(pt0+1)*32+c] + sAV[w][1][kk][c] + b1[c];
        x0 = x0 > 0.f ? x0 : 0.2f*x0;
        x1 = x1 > 0.f ? x1 : 0.2f*x1;
        a2_0 = fmaf(x0, w2r[c], a2_0);
        a2_1 = fmaf(x1, w2r[c], a2_1);
    }
    const float lt0 = a2_0 / tv, lt1 = a2_1 / tv;
    float m0 = lt0, m1 = lt1;
    m0 = fmaxf(m0, __shfl_xor(m0, 4));  m1 = fmaxf(m1, __shfl_xor(m1, 4));
    m0 = fmaxf(m0, __shfl_xor(m0, 8));  m1 = fmaxf(m1, __shfl_xor(m1, 8));
    m0 = fmaxf(m0, __shfl_xor(m0, 16)); m1 = fmaxf(m1, __shfl_xor(m1, 16));
    m0 = fmaxf(m0, __shfl_xor(m0, 32)); m1 = fmaxf(m1, __shfl_xor(m1, 32));
    const float e0 = expf(lt0 - m0), e1 = expf(lt1 - m1);
    float s0 = e0, s1 = e1;
    s0 += __shfl_xor(s0, 4);  s1 += __shfl_xor(s1, 4);
    s0 += __shfl_xor(s0, 8);  s1 += __shfl_xor(s1, 8);
    s0 += __shfl_xor(s0, 16); s1 += __shfl_xor(s1, 16);
    s0 += __shfl_xor(s0, 32); s1 += __shfl_xor(s1, 32);
    attw[pt0*64 + lane]     = e0 / s0;
    attw[(pt0+1)*64 + lane] = e1 / s1;
    rs[t]=ssum; rq[t]=ssq; __syncthreads();
    if (t < 64){
        atomicAdd(&bn0s[t], rs[t]+rs[t+64]+rs[t+128]+rs[t+192]);
        atomicAdd(&bn0q[t], rq[t]+rq[t+64]+rq[t+128]+rq[t+192]);
    }
}

// ------ fold BN into per-channel scale/shift ------
__global__ __launch_bounds__(128) void bn_finalize_kernel(const float* s, const float* q, fpp g, fpp b,
        float inv_cnt, int C, float* scale, float* shift){
    const int c = threadIdx.x;
    if (c < C){
        const float mu  = s[c]*inv_cnt;
        const float var = fmaxf(q[c]*inv_cnt - mu*mu, 0.f);
        const float sc  = g[c] * rsqrtf(var + 1e-5f);
        scale[c]=sc; shift[c] = b[c] - mu*sc;
    }
}

// ------ merged BN0 + SC finalize ------
__global__ __launch_bounds__(192) void bn_finalize2_kernel(const float* s0, const float* q0,
        fpp g0, fpp b0, const float* ss, const float* qs, fpp gs, fpp bs,
        float* sc0, float* sh0, float* scsc, float* shsc){
    const int c = threadIdx.x;
    if (c < 64){
        const float mu  = s0[c]*(1.0f/262144.0f);
        const float var = fmaxf(q0[c]*(1.0f/262144.0f) - mu*mu, 0.f);
        const float sc  = g0[c] * rsqrtf(var + 1e-5f);
        sc0[c]=sc; sh0[c]=b0[c]-mu*sc;
    } else {
        const int cc = c - 64;
        const float mu  = ss[cc]*(1.0f/16384.0f);
        const float var = fmaxf(qs[cc]*(1.0f/16384.0f) - mu*mu, 0.f);
        const float sc  = gs[cc] * rsqrtf(var + 1e-5f);
        scsc[cc]=sc; shsc[cc]=bs[cc]-mu*sc;
    }
}

// ====== MFMA conv1 v2: 512 threads (8 waves), wave = (M-tile, N-half).
//        LDS 37KB -> 4 blocks/CU x 8 waves = 32 waves/CU. ======
__global__ __launch_bounds__(512) void mfma_conv1_kernel(const int* idx, const float* U, const float* V,
        fpp w1, const float* sc0, const float* sh0, float* bn1s, float* bn1q,
        unsigned short* y1out){
    __shared__ __align__(16) short WH[64*72], WL[64*72];
    __shared__ __align__(16) short AH[64*72], AL[64*72];
    __shared__ float ssum[64], ssq[64];
    const int t = threadIdx.x, lane = t & 63, w = t >> 6;
    const int L = lane & 15, Q = lane >> 4;
    for (int i = t; i < 4096; i += 512){
        const float wv = w1[i];
        const short hh = f2bf(wv);
        const int n = i >> 6, k = i & 63;
        WH[n*72+k] = hh;
        WL[n*72+k] = f2bf(wv - bf2f(hh));
    }
    if (t < 64){ ssum[t]=0.f; ssq[t]=0.f; }
    __syncthreads();
    const int nbase = (w >> 2) * 2;          // N-half: tiles {0,1} or {2,3}
    short8 bh[2][2], bl[2][2];
    #pragma unroll
    for (int nt=0; nt<2; ++nt){
        #pragma unroll
        for (int ks=0; ks<2; ++ks){
            const int off = ((nbase+nt)*16+L)*72 + ks*32 + Q*8;
            bh[nt][ks] = *(const short8*)&WH[off];
            bl[nt][ks] = *(const short8*)&WL[off];
        }
    }
    const int m0 = (w & 3) * 16;
    const int r = t >> 3, c8 = (t & 7) * 8;  // staging: edge r, 8 channels
    float sacc[2] = {0,0}, qacc[2] = {0,0};
    for (int tile = 0; tile < T1; ++tile){
        __syncthreads();
        const int e0 = (blockIdx.x*T1 + tile) * 64;
        {
            const int s = e0 + r;
            const int p = s >> 4, q = idx[s];
            const float4* up = (const float4*)&U[p*64 + c8];
            const float4* vq = (const float4*)&V[q*64 + c8];
            #pragma unroll
            for (int b4=0; b4<2; ++b4){
                const float4 uv4 = up[b4];
                const float4 vv4 = vq[b4];
                const int c0 = c8 + b4*4;
                float av[4] = {uv4.x+vv4.x, uv4.y+vv4.y, uv4.z+vv4.z, uv4.w+vv4.w};
                short4v h4, l4;
                #pragma unroll
                for (int j=0;j<4;j++){
                    const int c = c0 + j;
                    const float a0 = fmaxf(fmaf(av[j], sc0[c], sh0[c]), 0.f);
                    const short hh = f2bf(a0);
                    h4[j] = hh;
                    l4[j] = f2bf(a0 - bf2f(hh));
                }
                *(short4v*)&AH[r*72 + c0] = h4;
                *(short4v*)&AL[r*72 + c0] = l4;
            }
        }
        __syncthreads();
        floatx4 acc[2];
        #pragma unroll
        for (int nt=0;nt<2;nt++) acc[nt] = (floatx4){0.f,0.f,0.f,0.f};
        #pragma unroll
        for (int ks=0; ks<2; ++ks){
            const int aoff = (m0 + L)*72 + ks*32 + Q*8;
            const short8 ah = *(const short8*)&AH[aoff];
            const short8 al = *(const short8*)&AL[aoff];
            #pragma unroll
            for (int nt=0;nt<2;nt++){
                acc[nt] = __builtin_amdgcn_mfma_f32_16x16x32_bf16(ah, bh[nt][ks], acc[nt], 0,0,0);
                acc[nt] = __builtin_amdgcn_mfma_f32_16x16x32_bf16(ah, bl[nt][ks], acc[nt], 0,0,0);
                acc[nt] = __builtin_amdgcn_mfma_f32_16x16x32_bf16(al, bh[nt][ks], acc[nt], 0,0,0);
            }
        }
        #pragma unroll
        for (int nt=0;nt<2;nt++){
            const int o = (nbase+nt)*16 + L;
            #pragma unroll
            for (int rr=0;rr<4;rr++){
                const float v = acc[nt][rr];
                y1out[(e0 + m0 + Q*4 + rr)*64 + o] = (unsigned short)f2bf(v);
                sacc[nt]+=v; qacc[nt]+=v*v;
            }
        }
    }
    #pragma unroll
    for (int nt=0;nt<2;nt++){
        atomicAdd(&ssum[(nbase+nt)*16+L], sacc[nt]);
        atomicAdd(&ssq [(nbase+nt)*16+L], qacc[nt]);
    }
    __syncthreads();
    if (t < 64){
        atomicAdd(&bn1s[t], ssum[t]);
        atomicAdd(&bn1q[t], ssq[t]);
    }
}

// ====== MFMA conv2 v4: 512 threads (8 waves), wave = (M-tile, N-half of 8 tiles).
//        LDS 56KB -> 2 blocks/CU x 8 waves = 16 waves/CU. ======
__global__ __launch_bounds__(512) void mfma_conv2_kernel(const unsigned short* y1in,
        fpp w2, const float* sc1, const float* sh1,
        float* bn2s, float* bn2q, unsigned short* y2out){
    __shared__ __align__(16) short WH2[128*72], WL2[128*72];
    __shared__ __align__(16) short AH[64*72], AL[64*72];
    __shared__ float ssum[128], ssq[128];
    const int t = threadIdx.x, lane = t & 63, w = t >> 6;
    const int L = lane & 15, Q = lane >> 4;
    for (int i = t; i < 8192; i += 512){
        const float wv = w2[i];
        const short hh = f2bf(wv);
        WH2[(i>>6)*72+(i&63)] = hh;
        WL2[(i>>6)*72+(i&63)] = f2bf(wv - bf2f(hh));
    }
    if (t < 128){ ssum[t]=0.f; ssq[t]=0.f; }
    const int nbase = (w >> 2) * 4;          // N-half: tiles {0..3} or {4..7}
    const int m0 = (w & 3) * 16;
    const int r = t >> 3, c8 = (t & 7) * 8;  // staging: edge r, 8 channels
    float s1r[8], h1r[8];
    #pragma unroll
    for (int j=0;j<8;j++){ s1r[j] = sc1[c8+j]; h1r[j] = sh1[c8+j]; }
    float sacc[4] = {0,0,0,0}, qacc[4] = {0,0,0,0};
    for (int tile = 0; tile < T1; ++tile){
        __syncthreads();
        const int e0 = (blockIdx.x*T1 + tile) * 64;
        {
            const short8 y8 = *(const short8*)&y1in[(e0 + r)*64 + c8];
            short4v h4, l4;
            #pragma unroll
            for (int g=0; g<2; ++g){
                #pragma unroll
                for (int j=0;j<4;j++){
                    const int jj = g*4 + j;
                    const float a1 = fmaxf(fmaf(bf2fu((unsigned short)y8[jj]),
                                                s1r[jj], h1r[jj]), 0.f);
                    const short hh = f2bf(a1);
                    h4[j] = hh;
                    l4[j] = f2bf(a1 - bf2f(hh));
                }
                const int c0 = c8 + g*4;
                *(short4v*)&AH[r*72 + c0] = h4;
                *(short4v*)&AL[r*72 + c0] = l4;
            }
        }
        __syncthreads();
        floatx4 acc2[4];
        #pragma unroll
        for (int nt=0;nt<4;nt++) acc2[nt] = (floatx4){0.f,0.f,0.f,0.f};
        #pragma unroll
        for (int ks=0; ks<2; ++ks){
            const int aoff = (m0 + L)*72 + ks*32 + Q*8;
            const short8 ah = *(const short8*)&AH[aoff];
            const short8 al = *(const short8*)&AL[aoff];
            #pragma unroll
            for (int nt=0;nt<4;nt++){
                const int boff = ((nbase+nt)*16+L)*72 + ks*32 + Q*8;
                const short8 wh = *(const short8*)&WH2[boff];
                const short8 wl = *(const short8*)&WL2[boff];
                acc2[nt] = __builtin_amdgcn_mfma_f32_16x16x32_bf16(ah, wh, acc2[nt], 0,0,0);
                acc2[nt] = __builtin_amdgcn_mfma_f32_16x16x32_bf16(ah, wl, acc2[nt], 0,0,0);
                acc2[nt] = __builtin_amdgcn_mfma_f32_16x16x32_bf16(al, wh, acc2[nt], 0,0,0);
            }
        }
        #pragma unroll
        for (int nt=0;nt<4;nt++){
            const int o = (nbase+nt)*16 + L;
            #pragma unroll
            for (int rr=0;rr<4;rr++){
                const float v = acc2[nt][rr];
                const int s = e0 + m0 + Q*4 + rr;
                y2out[s*128 + o] = (unsigned short)f2bf(v);
                sacc[nt] += v; qacc[nt] += v*v;
            }
        }
    }
    #pragma unroll
    for (int nt=0;nt<4;nt++){
        atomicAdd(&ssum[(nbase+nt)*16+L], sacc[nt]);
        atomicAdd(&ssq [(nbase+nt)*16+L], qacc[nt]);
    }
    __syncthreads();
    if (t < 128){
        atomicAdd(&bn2s[t], ssum[t]);
        atomicAdd(&bn2q[t], ssq[t]);
    }
}

// ------ combine v2: channel-pair per lane -> uint loads (4B/lane, coalesced),
//        one shared attw read per pair, float2 stores. Math identical. ------
__global__ __launch_bounds__(256) void combine_fast_kernel(const unsigned short* y2, const float* attw,
        const float* sc2, const float* sh2, float* xcomb, float* msum){
    __shared__ float rs[512];
    const int t=threadIdx.x, w=t>>6, lane=t&63;
    const int c0 = lane*2;
    const float s2a=sc2[c0], h2a=sh2[c0], s2b=sc2[c0+1], h2b=sh2[c0+1];
    const int pt0 = blockIdx.x*16 + w*4;
    const int hsel = lane >> 4;              // = c0>>5, same head for both channels
    float m0=0.f, m1=0.f;
    for (int j=0;j<4;j++){
        const int pt = pt0 + j;
        float acc0=0.f, acc1=0.f;
        for (int k=0;k<K_;k++){
            const int s = pt*K_ + k;
            const unsigned v = *(const unsigned*)&y2[s*128 + c0];
            const float aw = attw[s*4 + hsel];
            const float r0 = fmaxf(fmaf(bf2fu((unsigned short)(v & 0xFFFFu)), s2a, h2a), 0.f);
            const float r1 = fmaxf(fmaf(bf2fu((unsigned short)(v >> 16)),    s2b, h2b), 0.f);
            acc0 = fmaf(r0, aw, acc0);
            acc1 = fmaf(r1, aw, acc1);
        }
        *(float2*)&xcomb[pt*128 + c0] = make_float2(acc0, acc1);
        m0 += acc0; m1 += acc1;
    }
    rs[t]=m0; rs[256+t]=m1; __syncthreads();
    if (t<64){
        const int n = (blockIdx.x*16) >> 11;
        atomicAdd(&msum[n*128+2*t],   rs[t]+rs[t+64]+rs[t+128]+rs[t+192]);
        atomicAdd(&msum[n*128+2*t+1], rs[256+t]+rs[256+t+64]+rs[256+t+128]+rs[256+t+192]);
    }
}

// ------ final v3: SE gate fused in (se_kernel eliminated). 256 thr:
//        2 row-groups x 128 ch. Each block recomputes the tiny SE MLP
//        (~8K fma, redundant, negligible) for its (uniform) batch. ------
__global__ __launch_bounds__(256) void final_kernel(fpp feat, fpp scw, const float* xcomb,
        const float* msum, fpp w1se, fpp w2se,
        const float* scsc, const float* shsc, float* out){
    __shared__ float swc[128*65];
    __shared__ float sf[16*64];
    __shared__ float tl[32];
    const int t = threadIdx.x;
    for (int i=t;i<8192;i+=256) swc[(i>>6)*65+(i&63)] = scw[i];
    const int row0 = blockIdx.x*16;
    const int n = row0 >> 11;                // uniform: 2048 % 16 == 0
    for (int i=t;i<1024;i+=256) sf[i] = feat[row0*64+i];
    if (t < 32){
        float acc=0.f;
        for (int c=0;c<128;c++) acc = fmaf(msum[n*128+c]*(1.f/2048.f), w1se[t*128+c], acc);
        tl[t] = fmaxf(acc, 0.f);
    }
    __syncthreads();
    const int c = t & 127, rg = t >> 7;
    float acc2 = 0.f;
    for (int hh=0;hh<32;hh++) acc2 = fmaf(tl[hh], w2se[c*32+hh], acc2);
    const float sev = 1.f/(1.f+expf(-acc2));
    const float scl = scsc[c], shf = shsc[c];
    for (int r=rg*8; r<rg*8+8; r++){
        const int row = row0 + r;
        float acc = 0.f;
        #pragma unroll
        for (int k=0;k<64;k++) acc = fmaf(sf[r*64+k], swc[c*65+k], acc);
        out[row*128+c] = xcomb[row*128+c]*sev + fmaxf(fmaf(acc, scl, shf), 0.f);
    }
}

extern "C" void kernel_launch(void* const* d_in, const int* in_sizes, int n_in,
                              void* d_out, int out_size, void* d_ws, size_t ws_size,
                              hipStream_t stream) {
    fpp points  = (fpp)d_in[0];
    fpp feat    = (fpp)d_in[1];
    fpp conv_w0 = (fpp)d_in[2];
    fpp conv_w1 = (fpp)d_in[3];
    fpp conv_w2 = (fpp)d_in[4];
    fpp bn_g0 = (fpp)d_in[5],  bn_b0 = (fpp)d_in[6];
    fpp bn_g1 = (fpp)d_in[7],  bn_b1 = (fpp)d_in[8];
    fpp bn_g2 = (fpp)d_in[9],  bn_b2 = (fpp)d_in[10];
    fpp attn_w1 = (fpp)d_in[11], attn_b1 = (fpp)d_in[12];
    fpp attn_w2 = (fpp)d_in[13], attn_b2 = (fpp)d_in[14];
    fpp tau  = (fpp)d_in[15];
    fpp sc_w = (fpp)d_in[16], sc_g = (fpp)d_in[17], sc_b = (fpp)d_in[18];
    fpp se_w1 = (fpp)d_in[19], se_w2 = (fpp)d_in[20];

    float* W = (float*)d_ws;
    float* BN0S=W+0;    float* BN0Q=W+64;
    float* BN1S=W+128;  float* BN1Q=W+192;
    float* BN2S=W+256;  float* BN2Q=W+384;
    float* SCS =W+512;  float* SCQ =W+640;
    float* SC0 =W+768;  float* SH0 =W+832;
    float* SC1 =W+896;  float* SH1 =W+960;
    float* SC2 =W+1024; float* SH2 =W+1152;
    float* SCSC=W+1280; float* SHSC=W+1408;
    float* MSUM=W+1536; float* SEV =W+2560;
    int*   IDX  = (int*)(W + 4096);
    float* U    = W + 266240;
    float* V    = U + 1048576;
    float* AU   = V + 1048576;
    float* AV   = AU + 524288;
    float* ATTW = AV + 524288;
    float* XCOMB= ATTW + 1048576;                          // ends 6,557,696 floats
    unsigned short* Y2 = (unsigned short*)(W + 6557696);   // 33,554,432 ushort
    unsigned short* Y1 = Y2 + 33554432;                    // 16,777,216 ushort
    // PTS4 aliases XCOMB (knn finishes long before combine writes XCOMB)
    float4* PTS4 = (float4*)XCOMB;                         // 16384 float4 = 256 KB

    hipMemsetAsync(d_ws, 0, 4096*sizeof(float), stream);

    pts_prep_kernel<<<64, 256, 0, stream>>>(points, PTS4);
    knn_kernel<<<2048, 256, 0, stream>>>(PTS4, IDX);
    feat_gemm_kernel<<<1024, 320, 0, stream>>>(feat, conv_w0, attn_w1, sc_w,
                                               U, V, AU, AV, SCS, SCQ);
    attn_bn0_kernel<<<2048, 256, 0, stream>>>(IDX, U, V, AU, AV,
                                              attn_b1, attn_w2, attn_b2, tau,
                                              ATTW, BN0S, BN0Q);
    bn_finalize2_kernel<<<1, 192, 0, stream>>>(BN0S, BN0Q, bn_g0, bn_b0,
                                               SCS, SCQ, sc_g, sc_b,
                                               SC0, SH0, SCSC, SHSC);
    mfma_conv1_kernel<<<512, 512, 0, stream>>>(IDX, U, V, conv_w1, SC0, SH0,
                                               BN1S, BN1Q, Y1);
    bn_finalize_kernel<<<1, 128, 0, stream>>>(BN1S, BN1Q, bn_g1, bn_b1,
                                              1.0f/262144.0f, 64, SC1, SH1);
    mfma_conv2_kernel<<<512, 512, 0, stream>>>(Y1, conv_w2, SC1, SH1,
                                               BN2S, BN2Q, Y2);
    bn_finalize_kernel<<<1, 128, 0, stream>>>(BN2S, BN2Q, bn_g2, bn_b2,
                                              1.0f/262144.0f, 128, SC2, SH2);
    combine_fast_kernel<<<1024, 256, 0, stream>>>(Y2, ATTW, SC2, SH2, XCOMB, MSUM);
    final_kernel<<<1024, 256, 0, stream>>>(feat, sc_w, XCOMB, MSUM, se_w1, se_w2,
                                           SCSC, SHSC, (float*)d_out);
}

// Round 16
// 321.471 us; speedup vs baseline: 1.1922x; 1.1899x over previous
//
#include <hip/hip_runtime.h>
#include <hip/hip_bf16.h>

#define N_   8
#define P_   2048
#define K_   16
#define T1   8

typedef const float* fpp;
typedef __attribute__((ext_vector_type(8))) short short8;
typedef __attribute__((ext_vector_type(4))) short short4v;
typedef __attribute__((ext_vector_type(4))) float floatx4;

__device__ __forceinline__ float bcast(float v, int lane){
    return __uint_as_float(__builtin_amdgcn_readlane(__float_as_uint(v), (unsigned)lane));
}
__device__ __forceinline__ short f2bf(float f){
    unsigned u = __float_as_uint(f);
    unsigned r = (u + 0x7FFFu + ((u >> 16) & 1u)) >> 16;
    return (short)r;
}
__device__ __forceinline__ float bf2f(short s){
    return __uint_as_float(((unsigned)(unsigned short)s) << 16);
}
__device__ __forceinline__ float bf2fu(unsigned short s){
    return __uint_as_float(((unsigned)s) << 16);
}

// ------ pack points into float4 (x,y,z,|p|^2) once; L2-resident thereafter ------
__global__ __launch_bounds__(256) void pts_prep_kernel(fpp points, float4* pts4){
    const int i = blockIdx.x*256 + threadIdx.x;   // 16384 total
    const float x = points[i*3+0], y = points[i*3+1], z = points[i*3+2];
    pts4[i] = make_float4(x, y, z, x*x + y*y + z*z);
}

// ---- KNN v9 (proven: 59.9us, VALUBusy 60%): zero-LDS, instruction-dieted
//      insert machinery (readlane thr/dn, arithmetic qn, interleaved chains). ----
__global__ __launch_bounds__(256) void knn_kernel(const float4* pts4, int* idxo){
    const int t = threadIdx.x;
    const int wave = t >> 6, lane = t & 63;
    const int n  = blockIdx.x >> 8;           // 256 blocks per batch
    const int p0 = (blockIdx.x & 255) * 8;
    const int base = n << 11;
    const float4* cand = pts4 + base;
    const int plb = p0 + wave*2;
    float px[2], py[2], pz[2], rp[2];
    #pragma unroll
    for (int i=0;i<2;i++){
        const float4 me = cand[plb + i];
        px[i]=me.x; py[i]=me.y; pz[i]=me.z; rp[i]=me.w;
    }
    float sd[2]; int sq[2];
    {
        const float4 c = cand[lane];
        #pragma unroll
        for (int i=0;i<2;i++){
            sd[i] = (rp[i] - 2.0f*(px[i]*c.x + py[i]*c.y + pz[i]*c.z)) + c.w;
            sq[i] = lane;
        }
        #pragma unroll
        for (int k = 2; k <= 64; k <<= 1){
            #pragma unroll
            for (int j = k >> 1; j > 0; j >>= 1){
                const bool takeSmaller = ((lane & k) == 0) == ((lane & j) == 0);
                #pragma unroll
                for (int i=0;i<2;i++){
                    const float od = __shfl_xor(sd[i], j);
                    const int   oi = __shfl_xor(sq[i], j);
                    const bool otherLess = (od < sd[i]) || (od == sd[i] && oi < sq[i]);
                    const bool take = (takeSmaller == otherLess);
                    sd[i] = take ? od : sd[i];
                    sq[i] = take ? oi : sq[i];
                }
            }
        }
    }
    for (int s = 1; s < 32; ++s){
        const int ci0 = s*64;
        const float4 c = cand[ci0 + lane];
        float d[2]; unsigned long long mask[2];
        #pragma unroll
        for (int i=0;i<2;i++)
            d[i] = (rp[i] - 2.0f*(px[i]*c.x + py[i]*c.y + pz[i]*c.z)) + c.w;
        #pragma unroll
        for (int i=0;i<2;i++){
            const float thr = bcast(sd[i], 16);          // readlane, SALU
            mask[i] = __ballot(d[i] < thr);
        }
        // interleaved insert loops: the two serial shfl_up chains overlap
        while (mask[0] | mask[1]){
            #pragma unroll
            for (int i=0;i<2;i++){
                if (mask[i]){
                    const int src = __ffsll((long long)mask[i]) - 1;
                    mask[i] &= mask[i] - 1;
                    const float dn = bcast(d[i], src);   // readlane, uniform src
                    const int   qn = ci0 + src;          // pure arithmetic
                    float shd = __shfl_up(sd[i], 1);
                    int   shq = __shfl_up(sq[i], 1);
                    if (lane == 0) shd = -__builtin_inff();
                    const bool c1 = shd > dn;
                    const bool c2 = sd[i] > dn;
                    sq[i] = c1 ? shq : (c2 ? qn : sq[i]);
                    sd[i] = c1 ? shd : (c2 ? dn : sd[i]);
                }
            }
        }
    }
    if (lane >= 1 && lane <= 16){
        #pragma unroll
        for (int i=0;i<2;i++)
            idxo[(base + plb + i)*K_ + (lane - 1)] = base + sq[i];
    }
}

// ------ per-point transforms v3: 5 waves; SC stats atomics SLOTTED by 16
//        (1024 blocks -> 64-deep chains per address, was 1024-deep). ------
__global__ __launch_bounds__(320) void feat_gemm_kernel(fpp feat, fpp w0, fpp aw1, fpp scw,
        float* U, float* V, float* AU, float* AV, float* scs16, float* scq16){
    const int t = threadIdx.x;
    const int w = t >> 6, lane = t & 63;
    const int row0 = blockIdx.x * 16;
    float wreg[64];
    if (w == 0){
        #pragma unroll
        for (int c=0;c<64;c++) wreg[c] = w0[lane*128+c] - w0[lane*128+64+c];
    } else if (w == 1){
        #pragma unroll
        for (int c=0;c<64;c++) wreg[c] = w0[lane*128+64+c];
    } else if (w == 2){
        if (lane < 32){
            #pragma unroll
            for (int c=0;c<64;c++) wreg[c] = aw1[lane*128+c] - aw1[lane*128+64+c];
        } else {
            const int o = lane - 32;
            #pragma unroll
            for (int c=0;c<64;c++) wreg[c] = aw1[o*128+64+c];
        }
    } else {
        const int o = (w-3)*64 + lane;
        #pragma unroll
        for (int c=0;c<64;c++) wreg[c] = scw[o*64+c];
    }
    float psum=0.f, psq=0.f;
    for (int r=0;r<16;r++){
        const int row = row0 + r;
        const float fv = feat[row*64 + lane];
        float acc = 0.f;
        #pragma unroll
        for (int c=0;c<64;c++) acc = fmaf(bcast(fv, c), wreg[c], acc);
        if      (w==0) U[row*64+lane]=acc;
        else if (w==1) V[row*64+lane]=acc;
        else if (w==2){ if (lane<32) AU[row*32+lane]=acc; else AV[row*32+lane-32]=acc; }
        else { psum += acc; psq += acc*acc; }
    }
    if (w >= 3){
        const int o = (w-3)*64 + lane;
        const int slot = (blockIdx.x & 15) * 128;
        atomicAdd(&scs16[slot + o], psum);
        atomicAdd(&scq16[slot + o], psq);
    }
}

// ------ attention + BN0 stats v4: compute as v3 (2-pt ILP); BN0 atomics
//        SLOTTED by 32 (2048 blocks -> 64-deep chains, was 2048-deep =
//        ~56us serial tail that dominated the kernel). ------
__global__ __launch_bounds__(256) void attn_bn0_kernel(const int* idx, const float* U, const float* V,
        const float* AU, const float* AV, fpp b1, fpp w2, fpp b2, fpp tau,
        float* attw, float* bn0s32, float* bn0q32){
    __shared__ float sAV[4][2][16][36];
    __shared__ float rs[256], rq[256];
    const int t = threadIdx.x, w = t>>6, lane = t&63;
    const int pt0 = blockIdx.x*8 + w*2;
    const int kk = lane >> 2, h = lane & 3;
    float w2r[32];
    #pragma unroll
    for (int c=0;c<32;c++) w2r[c] = w2[h*32+c];
    const float b2v = b2[h];
    const float tv  = tau[0];
    const int* ip0 = idx + pt0*K_;
    const int* ip1 = idx + (pt0+1)*K_;
    {
        const int fl = lane >> 2, part = lane & 3;
        const int qf0 = ip0[fl], qf1 = ip1[fl];
        const float4 a0 = *(const float4*)&AV[qf0*32 + part*8];
        const float4 a1 = *(const float4*)&AV[qf0*32 + part*8 + 4];
        const float4 b0 = *(const float4*)&AV[qf1*32 + part*8];
        const float4 b1v= *(const float4*)&AV[qf1*32 + part*8 + 4];
        *(float4*)&sAV[w][0][fl][part*8]     = a0;
        *(float4*)&sAV[w][0][fl][part*8 + 4] = a1;
        *(float4*)&sAV[w][1][fl][part*8]     = b0;
        *(float4*)&sAV[w][1][fl][part*8 + 4] = b1v;
    }
    __builtin_amdgcn_wave_barrier();
    const float uv0 = U[pt0*64+lane];
    const float uv1 = U[(pt0+1)*64+lane];
    float ssum=0.f, ssq=0.f;
    for (int k=0;k<K_;k++){
        const int q0 = ip0[k], q1 = ip1[k];
        const float v0 = uv0 + V[q0*64+lane];
        const float v1 = uv1 + V[q1*64+lane];
        ssum += v0 + v1; ssq += v0*v0 + v1*v1;
    }
    float a2_0 = b2v, a2_1 = b2v;
    for (int c=0;c<32;c++){
        float x0 = AU[pt0*32+c]     + sAV[w][0][kk][c] + b1[c];
        float x1 = AU[(pt0+1)*32+c] + sAV[w][1][kk][c] + b1[c];
        x0 = x0 > 0.f ? x0 : 0.2f*x0;
        x1 = x1 > 0.f ? x1 : 0.2f*x1;
        a2_0 = fmaf(x0, w2r[c], a2_0);
        a2_1 = fmaf(x1, w2r[c], a2_1);
    }
    const float lt0 = a2_0 / tv, lt1 = a2_1 / tv;
    float m0 = lt0, m1 = lt1;
    m0 = fmaxf(m0, __shfl_xor(m0, 4));  m1 = fmaxf(m1, __shfl_xor(m1, 4));
    m0 = fmaxf(m0, __shfl_xor(m0, 8));  m1 = fmaxf(m1, __shfl_xor(m1, 8));
    m0 = fmaxf(m0, __shfl_xor(m0, 16)); m1 = fmaxf(m1, __shfl_xor(m1, 16));
    m0 = fmaxf(m0, __shfl_xor(m0, 32)); m1 = fmaxf(m1, __shfl_xor(m1, 32));
    const float e0 = expf(lt0 - m0), e1 = expf(lt1 - m1);
    float s0 = e0, s1 = e1;
    s0 += __shfl_xor(s0, 4);  s1 += __shfl_xor(s1, 4);
    s0 += __shfl_xor(s0, 8);  s1 += __shfl_xor(s1, 8);
    s0 += __shfl_xor(s0, 16); s1 += __shfl_xor(s1, 16);
    s0 += __shfl_xor(s0, 32); s1 += __shfl_xor(s1, 32);
    attw[pt0*64 + lane]     = e0 / s0;
    attw[(pt0+1)*64 + lane] = e1 / s1;
    rs[t]=ssum; rq[t]=ssq; __syncthreads();
    if (t < 64){
        const int slot = (blockIdx.x & 31) * 64;
        atomicAdd(&bn0s32[slot + t], rs[t]+rs[t+64]+rs[t+128]+rs[t+192]);
        atomicAdd(&bn0q32[slot + t], rq[t]+rq[t+64]+rq[t+128]+rq[t+192]);
    }
}

// ------ fold BN into per-channel scale/shift (slot-summing) ------
__global__ __launch_bounds__(128) void bn_finalize_kernel(const float* s, const float* q, fpp g, fpp b,
        float inv_cnt, int C, int nslots, float* scale, float* shift){
    const int c = threadIdx.x;
    if (c < C){
        float as=0.f, aq=0.f;
        for (int k=0;k<nslots;k++){ as += s[k*C+c]; aq += q[k*C+c]; }
        const float mu  = as*inv_cnt;
        const float var = fmaxf(aq*inv_cnt - mu*mu, 0.f);
        const float sc  = g[c] * rsqrtf(var + 1e-5f);
        scale[c]=sc; shift[c] = b[c] - mu*sc;
    }
}

// ------ merged BN0 + SC finalize (slot-summing: BN0 x32, SC x16) ------
__global__ __launch_bounds__(192) void bn_finalize2_kernel(const float* s0, const float* q0,
        fpp g0, fpp b0, const float* ss, const float* qs, fpp gs, fpp bs,
        float* sc0, float* sh0, float* scsc, float* shsc){
    const int c = threadIdx.x;
    if (c < 64){
        float as=0.f, aq=0.f;
        for (int k=0;k<32;k++){ as += s0[k*64+c]; aq += q0[k*64+c]; }
        const float mu  = as*(1.0f/262144.0f);
        const float var = fmaxf(aq*(1.0f/262144.0f) - mu*mu, 0.f);
        const float sc  = g0[c] * rsqrtf(var + 1e-5f);
        sc0[c]=sc; sh0[c]=b0[c]-mu*sc;
    } else {
        const int cc = c - 64;
        float as=0.f, aq=0.f;
        for (int k=0;k<16;k++){ as += ss[k*128+cc]; aq += qs[k*128+cc]; }
        const float mu  = as*(1.0f/16384.0f);
        const float var = fmaxf(aq*(1.0f/16384.0f) - mu*mu, 0.f);
        const float sc  = gs[cc] * rsqrtf(var + 1e-5f);
        scsc[cc]=sc; shsc[cc]=bs[cc]-mu*sc;
    }
}

// ====== MFMA conv1 v3: 8 waves; BN1 atomics slotted by 8 (512 blocks -> 64-deep). ======
__global__ __launch_bounds__(512) void mfma_conv1_kernel(const int* idx, const float* U, const float* V,
        fpp w1, const float* sc0, const float* sh0, float* bn1s8, float* bn1q8,
        unsigned short* y1out){
    __shared__ __align__(16) short WH[64*72], WL[64*72];
    __shared__ __align__(16) short AH[64*72], AL[64*72];
    __shared__ float ssum[64], ssq[64];
    const int t = threadIdx.x, lane = t & 63, w = t >> 6;
    const int L = lane & 15, Q = lane >> 4;
    for (int i = t; i < 4096; i += 512){
        const float wv = w1[i];
        const short hh = f2bf(wv);
        const int n = i >> 6, k = i & 63;
        WH[n*72+k] = hh;
        WL[n*72+k] = f2bf(wv - bf2f(hh));
    }
    if (t < 64){ ssum[t]=0.f; ssq[t]=0.f; }
    __syncthreads();
    const int nbase = (w >> 2) * 2;          // N-half: tiles {0,1} or {2,3}
    short8 bh[2][2], bl[2][2];
    #pragma unroll
    for (int nt=0; nt<2; ++nt){
        #pragma unroll
        for (int ks=0; ks<2; ++ks){
            const int off = ((nbase+nt)*16+L)*72 + ks*32 + Q*8;
            bh[nt][ks] = *(const short8*)&WH[off];
            bl[nt][ks] = *(const short8*)&WL[off];
        }
    }
    const int m0 = (w & 3) * 16;
    const int r = t >> 3, c8 = (t & 7) * 8;  // staging: edge r, 8 channels
    float sacc[2] = {0,0}, qacc[2] = {0,0};
    for (int tile = 0; tile < T1; ++tile){
        __syncthreads();
        const int e0 = (blockIdx.x*T1 + tile) * 64;
        {
            const int s = e0 + r;
            const int p = s >> 4, q = idx[s];
            const float4* up = (const float4*)&U[p*64 + c8];
            const float4* vq = (const float4*)&V[q*64 + c8];
            #pragma unroll
            for (int b4=0; b4<2; ++b4){
                const float4 uv4 = up[b4];
                const float4 vv4 = vq[b4];
                const int c0 = c8 + b4*4;
                float av[4] = {uv4.x+vv4.x, uv4.y+vv4.y, uv4.z+vv4.z, uv4.w+vv4.w};
                short4v h4, l4;
                #pragma unroll
                for (int j=0;j<4;j++){
                    const int c = c0 + j;
                    const float a0 = fmaxf(fmaf(av[j], sc0[c], sh0[c]), 0.f);
                    const short hh = f2bf(a0);
                    h4[j] = hh;
                    l4[j] = f2bf(a0 - bf2f(hh));
                }
                *(short4v*)&AH[r*72 + c0] = h4;
                *(short4v*)&AL[r*72 + c0] = l4;
            }
        }
        __syncthreads();
        floatx4 acc[2];
        #pragma unroll
        for (int nt=0;nt<2;nt++) acc[nt] = (floatx4){0.f,0.f,0.f,0.f};
        #pragma unroll
        for (int ks=0; ks<2; ++ks){
            const int aoff = (m0 + L)*72 + ks*32 + Q*8;
            const short8 ah = *(const short8*)&AH[aoff];
            const short8 al = *(const short8*)&AL[aoff];
            #pragma unroll
            for (int nt=0;nt<2;nt++){
                acc[nt] = __builtin_amdgcn_mfma_f32_16x16x32_bf16(ah, bh[nt][ks], acc[nt], 0,0,0);
                acc[nt] = __builtin_amdgcn_mfma_f32_16x16x32_bf16(ah, bl[nt][ks], acc[nt], 0,0,0);
                acc[nt] = __builtin_amdgcn_mfma_f32_16x16x32_bf16(al, bh[nt][ks], acc[nt], 0,0,0);
            }
        }
        #pragma unroll
        for (int nt=0;nt<2;nt++){
            const int o = (nbase+nt)*16 + L;
            #pragma unroll
            for (int rr=0;rr<4;rr++){
                const float v = acc[nt][rr];
                y1out[(e0 + m0 + Q*4 + rr)*64 + o] = (unsigned short)f2bf(v);
                sacc[nt]+=v; qacc[nt]+=v*v;
            }
        }
    }
    #pragma unroll
    for (int nt=0;nt<2;nt++){
        atomicAdd(&ssum[(nbase+nt)*16+L], sacc[nt]);
        atomicAdd(&ssq [(nbase+nt)*16+L], qacc[nt]);
    }
    __syncthreads();
    if (t < 64){
        const int slot = (blockIdx.x & 7) * 64;
        atomicAdd(&bn1s8[slot + t], ssum[t]);
        atomicAdd(&bn1q8[slot + t], ssq[t]);
    }
}

// ====== MFMA conv2 v5: 8 waves; BN2 atomics slotted by 8 (512 blocks -> 64-deep). ======
__global__ __launch_bounds__(512) void mfma_conv2_kernel(const unsigned short* y1in,
        fpp w2, const float* sc1, const float* sh1,
        float* bn2s8, float* bn2q8, unsigned short* y2out){
    __shared__ __align__(16) short WH2[128*72], WL2[128*72];
    __shared__ __align__(16) short AH[64*72], AL[64*72];
    __shared__ float ssum[128], ssq[128];
    const int t = threadIdx.x, lane = t & 63, w = t >> 6;
    const int L = lane & 15, Q = lane >> 4;
    for (int i = t; i < 8192; i += 512){
        const float wv = w2[i];
        const short hh = f2bf(wv);
        WH2[(i>>6)*72+(i&63)] = hh;
        WL2[(i>>6)*72+(i&63)] = f2bf(wv - bf2f(hh));
    }
    if (t < 128){ ssum[t]=0.f; ssq[t]=0.f; }
    const int nbase = (w >> 2) * 4;          // N-half: tiles {0..3} or {4..7}
    const int m0 = (w & 3) * 16;
    const int r = t >> 3, c8 = (t & 7) * 8;  // staging: edge r, 8 channels
    float s1r[8], h1r[8];
    #pragma unroll
    for (int j=0;j<8;j++){ s1r[j] = sc1[c8+j]; h1r[j] = sh1[c8+j]; }
    float sacc[4] = {0,0,0,0}, qacc[4] = {0,0,0,0};
    for (int tile = 0; tile < T1; ++tile){
        __syncthreads();
        const int e0 = (blockIdx.x*T1 + tile) * 64;
        {
            const short8 y8 = *(const short8*)&y1in[(e0 + r)*64 + c8];
            short4v h4, l4;
            #pragma unroll
            for (int g=0; g<2; ++g){
                #pragma unroll
                for (int j=0;j<4;j++){
                    const int jj = g*4 + j;
                    const float a1 = fmaxf(fmaf(bf2fu((unsigned short)y8[jj]),
                                                s1r[jj], h1r[jj]), 0.f);
                    const short hh = f2bf(a1);
                    h4[j] = hh;
                    l4[j] = f2bf(a1 - bf2f(hh));
                }
                const int c0 = c8 + g*4;
                *(short4v*)&AH[r*72 + c0] = h4;
                *(short4v*)&AL[r*72 + c0] = l4;
            }
        }
        __syncthreads();
        floatx4 acc2[4];
        #pragma unroll
        for (int nt=0;nt<4;nt++) acc2[nt] = (floatx4){0.f,0.f,0.f,0.f};
        #pragma unroll
        for (int ks=0; ks<2; ++ks){
            const int aoff = (m0 + L)*72 + ks*32 + Q*8;
            const short8 ah = *(const short8*)&AH[aoff];
            const short8 al = *(const short8*)&AL[aoff];
            #pragma unroll
            for (int nt=0;nt<4;nt++){
                const int boff = ((nbase+nt)*16+L)*72 + ks*32 + Q*8;
                const short8 wh = *(const short8*)&WH2[boff];
                const short8 wl = *(const short8*)&WL2[boff];
                acc2[nt] = __builtin_amdgcn_mfma_f32_16x16x32_bf16(ah, wh, acc2[nt], 0,0,0);
                acc2[nt] = __builtin_amdgcn_mfma_f32_16x16x32_bf16(ah, wl, acc2[nt], 0,0,0);
                acc2[nt] = __builtin_amdgcn_mfma_f32_16x16x32_bf16(al, wh, acc2[nt], 0,0,0);
            }
        }
        #pragma unroll
        for (int nt=0;nt<4;nt++){
            const int o = (nbase+nt)*16 + L;
            #pragma unroll
            for (int rr=0;rr<4;rr++){
                const float v = acc2[nt][rr];
                const int s = e0 + m0 + Q*4 + rr;
                y2out[s*128 + o] = (unsigned short)f2bf(v);
                sacc[nt] += v; qacc[nt] += v*v;
            }
        }
    }
    #pragma unroll
    for (int nt=0;nt<4;nt++){
        atomicAdd(&ssum[(nbase+nt)*16+L], sacc[nt]);
        atomicAdd(&ssq [(nbase+nt)*16+L], qacc[nt]);
    }
    __syncthreads();
    if (t < 128){
        const int slot = (blockIdx.x & 7) * 128;
        atomicAdd(&bn2s8[slot + t], ssum[t]);
        atomicAdd(&bn2q8[slot + t], ssq[t]);
    }
}

// ------ combine v2: channel-pair per lane -> uint loads (4B/lane, coalesced),
//        one shared attw read per pair, float2 stores. Math identical. ------
__global__ __launch_bounds__(256) void combine_fast_kernel(const unsigned short* y2, const float* attw,
        const float* sc2, const float* sh2, float* xcomb, float* msum){
    __shared__ float rs[512];
    const int t=threadIdx.x, w=t>>6, lane=t&63;
    const int c0 = lane*2;
    const float s2a=sc2[c0], h2a=sh2[c0], s2b=sc2[c0+1], h2b=sh2[c0+1];
    const int pt0 = blockIdx.x*16 + w*4;
    const int hsel = lane >> 4;              // = c0>>5, same head for both channels
    float m0=0.f, m1=0.f;
    for (int j=0;j<4;j++){
        const int pt = pt0 + j;
        float acc0=0.f, acc1=0.f;
        for (int k=0;k<K_;k++){
            const int s = pt*K_ + k;
            const unsigned v = *(const unsigned*)&y2[s*128 + c0];
            const float aw = attw[s*4 + hsel];
            const float r0 = fmaxf(fmaf(bf2fu((unsigned short)(v & 0xFFFFu)), s2a, h2a), 0.f);
            const float r1 = fmaxf(fmaf(bf2fu((unsigned short)(v >> 16)),    s2b, h2b), 0.f);
            acc0 = fmaf(r0, aw, acc0);
            acc1 = fmaf(r1, aw, acc1);
        }
        *(float2*)&xcomb[pt*128 + c0] = make_float2(acc0, acc1);
        m0 += acc0; m1 += acc1;
    }
    rs[t]=m0; rs[256+t]=m1; __syncthreads();
    if (t<64){
        const int n = (blockIdx.x*16) >> 11;
        atomicAdd(&msum[n*128+2*t],   rs[t]+rs[t+64]+rs[t+128]+rs[t+192]);
        atomicAdd(&msum[n*128+2*t+1], rs[256+t]+rs[256+t+64]+rs[256+t+128]+rs[256+t+192]);
    }
}

// ------ final v3: SE gate fused in. 256 thr: 2 row-groups x 128 ch. ------
__global__ __launch_bounds__(256) void final_kernel(fpp feat, fpp scw, const float* xcomb,
        const float* msum, fpp w1se, fpp w2se,
        const float* scsc, const float* shsc, float* out){
    __shared__ float swc[128*65];
    __shared__ float sf[16*64];
    __shared__ float tl[32];
    const int t = threadIdx.x;
    for (int i=t;i<8192;i+=256) swc[(i>>6)*65+(i&63)] = scw[i];
    const int row0 = blockIdx.x*16;
    const int n = row0 >> 11;                // uniform: 2048 % 16 == 0
    for (int i=t;i<1024;i+=256) sf[i] = feat[row0*64+i];
    if (t < 32){
        float acc=0.f;
        for (int c=0;c<128;c++) acc = fmaf(msum[n*128+c]*(1.f/2048.f), w1se[t*128+c], acc);
        tl[t] = fmaxf(acc, 0.f);
    }
    __syncthreads();
    const int c = t & 127, rg = t >> 7;
    float acc2 = 0.f;
    for (int hh=0;hh<32;hh++) acc2 = fmaf(tl[hh], w2se[c*32+hh], acc2);
    const float sev = 1.f/(1.f+expf(-acc2));
    const float scl = scsc[c], shf = shsc[c];
    for (int r=rg*8; r<rg*8+8; r++){
        const int row = row0 + r;
        float acc = 0.f;
        #pragma unroll
        for (int k=0;k<64;k++) acc = fmaf(sf[r*64+k], swc[c*65+k], acc);
        out[row*128+c] = xcomb[row*128+c]*sev + fmaxf(fmaf(acc, scl, shf), 0.f);
    }
}

extern "C" void kernel_launch(void* const* d_in, const int* in_sizes, int n_in,
                              void* d_out, int out_size, void* d_ws, size_t ws_size,
                              hipStream_t stream) {
    fpp points  = (fpp)d_in[0];
    fpp feat    = (fpp)d_in[1];
    fpp conv_w0 = (fpp)d_in[2];
    fpp conv_w1 = (fpp)d_in[3];
    fpp conv_w2 = (fpp)d_in[4];
    fpp bn_g0 = (fpp)d_in[5],  bn_b0 = (fpp)d_in[6];
    fpp bn_g1 = (fpp)d_in[7],  bn_b1 = (fpp)d_in[8];
    fpp bn_g2 = (fpp)d_in[9],  bn_b2 = (fpp)d_in[10];
    fpp attn_w1 = (fpp)d_in[11], attn_b1 = (fpp)d_in[12];
    fpp attn_w2 = (fpp)d_in[13], attn_b2 = (fpp)d_in[14];
    fpp tau  = (fpp)d_in[15];
    fpp sc_w = (fpp)d_in[16], sc_g = (fpp)d_in[17], sc_b = (fpp)d_in[18];
    fpp se_w1 = (fpp)d_in[19], se_w2 = (fpp)d_in[20];

    float* W = (float*)d_ws;
    // scalar outputs of finalize kernels:
    float* SC0 =W+768;  float* SH0 =W+832;
    float* SC1 =W+896;  float* SH1 =W+960;
    float* SC2 =W+1024; float* SH2 =W+1152;
    float* SCSC=W+1280; float* SHSC=W+1408;
    float* MSUM=W+1536;
    // slotted atomic stat arrays (all inside first 16384-float memset):
    float* BN0S32=W+4096;  float* BN0Q32=W+6144;    // 32 x 64
    float* BN1S8 =W+8192;  float* BN1Q8 =W+8704;    // 8 x 64
    float* BN2S8 =W+9216;  float* BN2Q8 =W+10240;   // 8 x 128
    float* SCS16 =W+11264; float* SCQ16 =W+13312;   // 16 x 128
    int*   IDX  = (int*)(W + 16384);                 // 262144 ints -> ends 278528
    float* U    = W + 278528;
    float* V    = U + 1048576;
    float* AU   = V + 1048576;
    float* AV   = AU + 524288;
    float* ATTW = AV + 524288;
    float* XCOMB= ATTW + 1048576;                    // 2097152 floats -> ends 6569984
    unsigned short* Y2 = (unsigned short*)(W + 6569984);   // 33,554,432 ushort
    unsigned short* Y1 = Y2 + 33554432;                    // 16,777,216 ushort
    // PTS4 aliases XCOMB (knn finishes long before combine writes XCOMB)
    float4* PTS4 = (float4*)XCOMB;                   // 16384 float4 = 256 KB

    hipMemsetAsync(d_ws, 0, 16384*sizeof(float), stream);

    pts_prep_kernel<<<64, 256, 0, stream>>>(points, PTS4);
    knn_kernel<<<2048, 256, 0, stream>>>(PTS4, IDX);
    feat_gemm_kernel<<<1024, 320, 0, stream>>>(feat, conv_w0, attn_w1, sc_w,
                                               U, V, AU, AV, SCS16, SCQ16);
    attn_bn0_kernel<<<2048, 256, 0, stream>>>(IDX, U, V, AU, AV,
                                              attn_b1, attn_w2, attn_b2, tau,
                                              ATTW, BN0S32, BN0Q32);
    bn_finalize2_kernel<<<1, 192, 0, stream>>>(BN0S32, BN0Q32, bn_g0, bn_b0,
                                               SCS16, SCQ16, sc_g, sc_b,
                                               SC0, SH0, SCSC, SHSC);
    mfma_conv1_kernel<<<512, 512, 0, stream>>>(IDX, U, V, conv_w1, SC0, SH0,
                                               BN1S8, BN1Q8, Y1);
    bn_finalize_kernel<<<1, 128, 0, stream>>>(BN1S8, BN1Q8, bn_g1, bn_b1,
                                              1.0f/262144.0f, 64, 8, SC1, SH1);
    mfma_conv2_kernel<<<512, 512, 0, stream>>>(Y1, conv_w2, SC1, SH1,
                                               BN2S8, BN2Q8, Y2);
    bn_finalize_kernel<<<1, 128, 0, stream>>>(BN2S8, BN2Q8, bn_g2, bn_b2,
                                              1.0f/262144.0f, 128, 8, SC2, SH2);
    combine_fast_kernel<<<1024, 256, 0, stream>>>(Y2, ATTW, SC2, SH2, XCOMB, MSUM);
    final_kernel<<<1024, 256, 0, stream>>>(feat, sc_w, XCOMB, MSUM, se_w1, se_w2,
                                           SCSC, SHSC, (float*)d_out);
}

// Round 18
// 310.191 us; speedup vs baseline: 1.2356x; 1.0364x over previous
//
#include <hip/hip_runtime.h>
#include <hip/hip_bf16.h>

#define N_   8
#define P_   2048
#define K_   16
#define T1   8

typedef const float* fpp;
typedef __attribute__((ext_vector_type(8))) short short8;
typedef __attribute__((ext_vector_type(4))) short short4v;
typedef __attribute__((ext_vector_type(4))) float floatx4;

__device__ __forceinline__ float bcast(float v, int lane){
    return __uint_as_float(__builtin_amdgcn_readlane(__float_as_uint(v), (unsigned)lane));
}
__device__ __forceinline__ short f2bf(float f){
    unsigned u = __float_as_uint(f);
    unsigned r = (u + 0x7FFFu + ((u >> 16) & 1u)) >> 16;
    return (short)r;
}
__device__ __forceinline__ float bf2f(short s){
    return __uint_as_float(((unsigned)(unsigned short)s) << 16);
}
__device__ __forceinline__ float bf2fu(unsigned short s){
    return __uint_as_float(((unsigned)s) << 16);
}

// ------ pack points into float4 (x,y,z,|p|^2) once; L2-resident thereafter ------
__global__ __launch_bounds__(256) void pts_prep_kernel(fpp points, float4* pts4){
    const int i = blockIdx.x*256 + threadIdx.x;   // 16384 total
    const float x = points[i*3+0], y = points[i*3+1], z = points[i*3+2];
    pts4[i] = make_float4(x, y, z, x*x + y*y + z*z);
}

// ---- KNN v9 (proven: 59.9us, VALUBusy 60%): zero-LDS, instruction-dieted
//      insert machinery (readlane thr/dn, arithmetic qn, interleaved chains). ----
__global__ __launch_bounds__(256) void knn_kernel(const float4* pts4, int* idxo){
    const int t = threadIdx.x;
    const int wave = t >> 6, lane = t & 63;
    const int n  = blockIdx.x >> 8;           // 256 blocks per batch
    const int p0 = (blockIdx.x & 255) * 8;
    const int base = n << 11;
    const float4* cand = pts4 + base;
    const int plb = p0 + wave*2;
    float px[2], py[2], pz[2], rp[2];
    #pragma unroll
    for (int i=0;i<2;i++){
        const float4 me = cand[plb + i];
        px[i]=me.x; py[i]=me.y; pz[i]=me.z; rp[i]=me.w;
    }
    float sd[2]; int sq[2];
    {
        const float4 c = cand[lane];
        #pragma unroll
        for (int i=0;i<2;i++){
            sd[i] = (rp[i] - 2.0f*(px[i]*c.x + py[i]*c.y + pz[i]*c.z)) + c.w;
            sq[i] = lane;
        }
        #pragma unroll
        for (int k = 2; k <= 64; k <<= 1){
            #pragma unroll
            for (int j = k >> 1; j > 0; j >>= 1){
                const bool takeSmaller = ((lane & k) == 0) == ((lane & j) == 0);
                #pragma unroll
                for (int i=0;i<2;i++){
                    const float od = __shfl_xor(sd[i], j);
                    const int   oi = __shfl_xor(sq[i], j);
                    const bool otherLess = (od < sd[i]) || (od == sd[i] && oi < sq[i]);
                    const bool take = (takeSmaller == otherLess);
                    sd[i] = take ? od : sd[i];
                    sq[i] = take ? oi : sq[i];
                }
            }
        }
    }
    for (int s = 1; s < 32; ++s){
        const int ci0 = s*64;
        const float4 c = cand[ci0 + lane];
        float d[2]; unsigned long long mask[2];
        #pragma unroll
        for (int i=0;i<2;i++)
            d[i] = (rp[i] - 2.0f*(px[i]*c.x + py[i]*c.y + pz[i]*c.z)) + c.w;
        #pragma unroll
        for (int i=0;i<2;i++){
            const float thr = bcast(sd[i], 16);          // readlane, SALU
            mask[i] = __ballot(d[i] < thr);
        }
        // interleaved insert loops: the two serial shfl_up chains overlap
        while (mask[0] | mask[1]){
            #pragma unroll
            for (int i=0;i<2;i++){
                if (mask[i]){
                    const int src = __ffsll((long long)mask[i]) - 1;
                    mask[i] &= mask[i] - 1;
                    const float dn = bcast(d[i], src);   // readlane, uniform src
                    const int   qn = ci0 + src;          // pure arithmetic
                    float shd = __shfl_up(sd[i], 1);
                    int   shq = __shfl_up(sq[i], 1);
                    if (lane == 0) shd = -__builtin_inff();
                    const bool c1 = shd > dn;
                    const bool c2 = sd[i] > dn;
                    sq[i] = c1 ? shq : (c2 ? qn : sq[i]);
                    sd[i] = c1 ? shd : (c2 ? dn : sd[i]);
                }
            }
        }
    }
    if (lane >= 1 && lane <= 16){
        #pragma unroll
        for (int i=0;i<2;i++)
            idxo[(base + plb + i)*K_ + (lane - 1)] = base + sq[i];
    }
}

// ------ per-point transforms v3: 5 waves; SC stats atomics SLOTTED by 16 ------
__global__ __launch_bounds__(320) void feat_gemm_kernel(fpp feat, fpp w0, fpp aw1, fpp scw,
        float* U, float* V, float* AU, float* AV, float* scs16, float* scq16){
    const int t = threadIdx.x;
    const int w = t >> 6, lane = t & 63;
    const int row0 = blockIdx.x * 16;
    float wreg[64];
    if (w == 0){
        #pragma unroll
        for (int c=0;c<64;c++) wreg[c] = w0[lane*128+c] - w0[lane*128+64+c];
    } else if (w == 1){
        #pragma unroll
        for (int c=0;c<64;c++) wreg[c] = w0[lane*128+64+c];
    } else if (w == 2){
        if (lane < 32){
            #pragma unroll
            for (int c=0;c<64;c++) wreg[c] = aw1[lane*128+c] - aw1[lane*128+64+c];
        } else {
            const int o = lane - 32;
            #pragma unroll
            for (int c=0;c<64;c++) wreg[c] = aw1[o*128+64+c];
        }
    } else {
        const int o = (w-3)*64 + lane;
        #pragma unroll
        for (int c=0;c<64;c++) wreg[c] = scw[o*64+c];
    }
    float psum=0.f, psq=0.f;
    for (int r=0;r<16;r++){
        const int row = row0 + r;
        const float fv = feat[row*64 + lane];
        float acc = 0.f;
        #pragma unroll
        for (int c=0;c<64;c++) acc = fmaf(bcast(fv, c), wreg[c], acc);
        if      (w==0) U[row*64+lane]=acc;
        else if (w==1) V[row*64+lane]=acc;
        else if (w==2){ if (lane<32) AU[row*32+lane]=acc; else AV[row*32+lane-32]=acc; }
        else { psum += acc; psq += acc*acc; }
    }
    if (w >= 3){
        const int o = (w-3)*64 + lane;
        const int slot = (blockIdx.x & 15) * 128;
        atomicAdd(&scs16[slot + o], psum);
        atomicAdd(&scq16[slot + o], psq);
    }
}

// ------ attention + BN0 stats v4: 2-pt ILP; BN0 atomics slotted by 32 ------
__global__ __launch_bounds__(256) void attn_bn0_kernel(const int* idx, const float* U, const float* V,
        const float* AU, const float* AV, fpp b1, fpp w2, fpp b2, fpp tau,
        float* attw, float* bn0s32, float* bn0q32){
    __shared__ float sAV[4][2][16][36];
    __shared__ float rs[256], rq[256];
    const int t = threadIdx.x, w = t>>6, lane = t&63;
    const int pt0 = blockIdx.x*8 + w*2;
    const int kk = lane >> 2, h = lane & 3;
    float w2r[32];
    #pragma unroll
    for (int c=0;c<32;c++) w2r[c] = w2[h*32+c];
    const float b2v = b2[h];
    const float tv  = tau[0];
    const int* ip0 = idx + pt0*K_;
    const int* ip1 = idx + (pt0+1)*K_;
    {
        const int fl = lane >> 2, part = lane & 3;
        const int qf0 = ip0[fl], qf1 = ip1[fl];
        const float4 a0 = *(const float4*)&AV[qf0*32 + part*8];
        const float4 a1 = *(const float4*)&AV[qf0*32 + part*8 + 4];
        const float4 b0 = *(const float4*)&AV[qf1*32 + part*8];
        const float4 b1v= *(const float4*)&AV[qf1*32 + part*8 + 4];
        *(float4*)&sAV[w][0][fl][part*8]     = a0;
        *(float4*)&sAV[w][0][fl][part*8 + 4] = a1;
        *(float4*)&sAV[w][1][fl][part*8]     = b0;
        *(float4*)&sAV[w][1][fl][part*8 + 4] = b1v;
    }
    __builtin_amdgcn_wave_barrier();
    const float uv0 = U[pt0*64+lane];
    const float uv1 = U[(pt0+1)*64+lane];
    float ssum=0.f, ssq=0.f;
    for (int k=0;k<K_;k++){
        const int q0 = ip0[k], q1 = ip1[k];
        const float v0 = uv0 + V[q0*64+lane];
        const float v1 = uv1 + V[q1*64+lane];
        ssum += v0 + v1; ssq += v0*v0 + v1*v1;
    }
    float a2_0 = b2v, a2_1 = b2v;
    for (int c=0;c<32;c++){
        float x0 = AU[pt0*32+c]     + sAV[w][0][kk][c] + b1[c];
        float x1 = AU[(pt0+1)*32+c] + sAV[w][1][kk][c] + b1[c];
        x0 = x0 > 0.f ? x0 : 0.2f*x0;
        x1 = x1 > 0.f ? x1 : 0.2f*x1;
        a2_0 = fmaf(x0, w2r[c], a2_0);
        a2_1 = fmaf(x1, w2r[c], a2_1);
    }
    const float lt0 = a2_0 / tv, lt1 = a2_1 / tv;
    float m0 = lt0, m1 = lt1;
    m0 = fmaxf(m0, __shfl_xor(m0, 4));  m1 = fmaxf(m1, __shfl_xor(m1, 4));
    m0 = fmaxf(m0, __shfl_xor(m0, 8));  m1 = fmaxf(m1, __shfl_xor(m1, 8));
    m0 = fmaxf(m0, __shfl_xor(m0, 16)); m1 = fmaxf(m1, __shfl_xor(m1, 16));
    m0 = fmaxf(m0, __shfl_xor(m0, 32)); m1 = fmaxf(m1, __shfl_xor(m1, 32));
    const float e0 = expf(lt0 - m0), e1 = expf(lt1 - m1);
    float s0 = e0, s1 = e1;
    s0 += __shfl_xor(s0, 4);  s1 += __shfl_xor(s1, 4);
    s0 += __shfl_xor(s0, 8);  s1 += __shfl_xor(s1, 8);
    s0 += __shfl_xor(s0, 16); s1 += __shfl_xor(s1, 16);
    s0 += __shfl_xor(s0, 32); s1 += __shfl_xor(s1, 32);
    attw[pt0*64 + lane]     = e0 / s0;
    attw[(pt0+1)*64 + lane] = e1 / s1;
    rs[t]=ssum; rq[t]=ssq; __syncthreads();
    if (t < 64){
        const int slot = (blockIdx.x & 31) * 64;
        atomicAdd(&bn0s32[slot + t], rs[t]+rs[t+64]+rs[t+128]+rs[t+192]);
        atomicAdd(&bn0q32[slot + t], rq[t]+rq[t+64]+rq[t+128]+rq[t+192]);
    }
}

// ====== MFMA conv1 v4: BN0 finalize folded in (each block derives SC0/SH0
//        from the 32 BN0 slots; ~2K L2-hot reads, bit-identical per block). ======
__global__ __launch_bounds__(512) void mfma_conv1_kernel(const int* idx, const float* U, const float* V,
        fpp w1, const float* bn0s32, const float* bn0q32, fpp g0, fpp b0,
        float* bn1s8, float* bn1q8, unsigned short* y1out){
    __shared__ __align__(16) short WH[64*72], WL[64*72];
    __shared__ __align__(16) short AH[64*72], AL[64*72];
    __shared__ float ssum[64], ssq[64];
    __shared__ float sSC0[64], sSH0[64];
    const int t = threadIdx.x, lane = t & 63, w = t >> 6;
    const int L = lane & 15, Q = lane >> 4;
    for (int i = t; i < 4096; i += 512){
        const float wv = w1[i];
        const short hh = f2bf(wv);
        const int n = i >> 6, k = i & 63;
        WH[n*72+k] = hh;
        WL[n*72+k] = f2bf(wv - bf2f(hh));
    }
    if (t < 64){
        ssum[t]=0.f; ssq[t]=0.f;
        float as=0.f, aq=0.f;
        for (int k=0;k<32;k++){ as += bn0s32[k*64+t]; aq += bn0q32[k*64+t]; }
        const float mu  = as*(1.0f/262144.0f);
        const float var = fmaxf(aq*(1.0f/262144.0f) - mu*mu, 0.f);
        const float sc  = g0[t] * rsqrtf(var + 1e-5f);
        sSC0[t]=sc; sSH0[t]=b0[t]-mu*sc;
    }
    __syncthreads();
    const int nbase = (w >> 2) * 2;          // N-half: tiles {0,1} or {2,3}
    short8 bh[2][2], bl[2][2];
    #pragma unroll
    for (int nt=0; nt<2; ++nt){
        #pragma unroll
        for (int ks=0; ks<2; ++ks){
            const int off = ((nbase+nt)*16+L)*72 + ks*32 + Q*8;
            bh[nt][ks] = *(const short8*)&WH[off];
            bl[nt][ks] = *(const short8*)&WL[off];
        }
    }
    const int m0 = (w & 3) * 16;
    const int r = t >> 3, c8 = (t & 7) * 8;  // staging: edge r, 8 channels
    float sacc[2] = {0,0}, qacc[2] = {0,0};
    for (int tile = 0; tile < T1; ++tile){
        __syncthreads();
        const int e0 = (blockIdx.x*T1 + tile) * 64;
        {
            const int s = e0 + r;
            const int p = s >> 4, q = idx[s];
            const float4* up = (const float4*)&U[p*64 + c8];
            const float4* vq = (const float4*)&V[q*64 + c8];
            #pragma unroll
            for (int b4=0; b4<2; ++b4){
                const float4 uv4 = up[b4];
                const float4 vv4 = vq[b4];
                const int c0 = c8 + b4*4;
                float av[4] = {uv4.x+vv4.x, uv4.y+vv4.y, uv4.z+vv4.z, uv4.w+vv4.w};
                short4v h4, l4;
                #pragma unroll
                for (int j=0;j<4;j++){
                    const int c = c0 + j;
                    const float a0 = fmaxf(fmaf(av[j], sSC0[c], sSH0[c]), 0.f);
                    const short hh = f2bf(a0);
                    h4[j] = hh;
                    l4[j] = f2bf(a0 - bf2f(hh));
                }
                *(short4v*)&AH[r*72 + c0] = h4;
                *(short4v*)&AL[r*72 + c0] = l4;
            }
        }
        __syncthreads();
        floatx4 acc[2];
        #pragma unroll
        for (int nt=0;nt<2;nt++) acc[nt] = (floatx4){0.f,0.f,0.f,0.f};
        #pragma unroll
        for (int ks=0; ks<2; ++ks){
            const int aoff = (m0 + L)*72 + ks*32 + Q*8;
            const short8 ah = *(const short8*)&AH[aoff];
            const short8 al = *(const short8*)&AL[aoff];
            #pragma unroll
            for (int nt=0;nt<2;nt++){
                acc[nt] = __builtin_amdgcn_mfma_f32_16x16x32_bf16(ah, bh[nt][ks], acc[nt], 0,0,0);
                acc[nt] = __builtin_amdgcn_mfma_f32_16x16x32_bf16(ah, bl[nt][ks], acc[nt], 0,0,0);
                acc[nt] = __builtin_amdgcn_mfma_f32_16x16x32_bf16(al, bh[nt][ks], acc[nt], 0,0,0);
            }
        }
        #pragma unroll
        for (int nt=0;nt<2;nt++){
            const int o = (nbase+nt)*16 + L;
            #pragma unroll
            for (int rr=0;rr<4;rr++){
                const float v = acc[nt][rr];
                y1out[(e0 + m0 + Q*4 + rr)*64 + o] = (unsigned short)f2bf(v);
                sacc[nt]+=v; qacc[nt]+=v*v;
            }
        }
    }
    #pragma unroll
    for (int nt=0;nt<2;nt++){
        atomicAdd(&ssum[(nbase+nt)*16+L], sacc[nt]);
        atomicAdd(&ssq [(nbase+nt)*16+L], qacc[nt]);
    }
    __syncthreads();
    if (t < 64){
        const int slot = (blockIdx.x & 7) * 64;
        atomicAdd(&bn1s8[slot + t], ssum[t]);
        atomicAdd(&bn1q8[slot + t], ssq[t]);
    }
}

// ====== MFMA conv2 v6: BN1 finalize folded in (SC1/SH1 from 8 slots). ======
__global__ __launch_bounds__(512) void mfma_conv2_kernel(const unsigned short* y1in,
        fpp w2, const float* bn1s8, const float* bn1q8, fpp g1, fpp b1g,
        float* bn2s8, float* bn2q8, unsigned short* y2out){
    __shared__ __align__(16) short WH2[128*72], WL2[128*72];
    __shared__ __align__(16) short AH[64*72], AL[64*72];
    __shared__ float ssum[128], ssq[128];
    __shared__ float sSC1[64], sSH1[64];
    const int t = threadIdx.x, lane = t & 63, w = t >> 6;
    const int L = lane & 15, Q = lane >> 4;
    for (int i = t; i < 8192; i += 512){
        const float wv = w2[i];
        const short hh = f2bf(wv);
        WH2[(i>>6)*72+(i&63)] = hh;
        WL2[(i>>6)*72+(i&63)] = f2bf(wv - bf2f(hh));
    }
    if (t < 128){ ssum[t]=0.f; ssq[t]=0.f; }
    if (t < 64){
        float as=0.f, aq=0.f;
        for (int k=0;k<8;k++){ as += bn1s8[k*64+t]; aq += bn1q8[k*64+t]; }
        const float mu  = as*(1.0f/262144.0f);
        const float var = fmaxf(aq*(1.0f/262144.0f) - mu*mu, 0.f);
        const float sc  = g1[t] * rsqrtf(var + 1e-5f);
        sSC1[t]=sc; sSH1[t]=b1g[t]-mu*sc;
    }
    __syncthreads();
    const int nbase = (w >> 2) * 4;          // N-half: tiles {0..3} or {4..7}
    const int m0 = (w & 3) * 16;
    const int r = t >> 3, c8 = (t & 7) * 8;  // staging: edge r, 8 channels
    float s1r[8], h1r[8];
    #pragma unroll
    for (int j=0;j<8;j++){ s1r[j] = sSC1[c8+j]; h1r[j] = sSH1[c8+j]; }
    float sacc[4] = {0,0,0,0}, qacc[4] = {0,0,0,0};
    for (int tile = 0; tile < T1; ++tile){
        __syncthreads();
        const int e0 = (blockIdx.x*T1 + tile) * 64;
        {
            const short8 y8 = *(const short8*)&y1in[(e0 + r)*64 + c8];
            short4v h4, l4;
            #pragma unroll
            for (int g=0; g<2; ++g){
                #pragma unroll
                for (int j=0;j<4;j++){
                    const int jj = g*4 + j;
                    const float a1 = fmaxf(fmaf(bf2fu((unsigned short)y8[jj]),
                                                s1r[jj], h1r[jj]), 0.f);
                    const short hh = f2bf(a1);
                    h4[j] = hh;
                    l4[j] = f2bf(a1 - bf2f(hh));
                }
                const int c0 = c8 + g*4;
                *(short4v*)&AH[r*72 + c0] = h4;
                *(short4v*)&AL[r*72 + c0] = l4;
            }
        }
        __syncthreads();
        floatx4 acc2[4];
        #pragma unroll
        for (int nt=0;nt<4;nt++) acc2[nt] = (floatx4){0.f,0.f,0.f,0.f};
        #pragma unroll
        for (int ks=0; ks<2; ++ks){
            const int aoff = (m0 + L)*72 + ks*32 + Q*8;
            const short8 ah = *(const short8*)&AH[aoff];
            const short8 al = *(const short8*)&AL[aoff];
            #pragma unroll
            for (int nt=0;nt<4;nt++){
                const int boff = ((nbase+nt)*16+L)*72 + ks*32 + Q*8;
                const short8 wh = *(const short8*)&WH2[boff];
                const short8 wl = *(const short8*)&WL2[boff];
                acc2[nt] = __builtin_amdgcn_mfma_f32_16x16x32_bf16(ah, wh, acc2[nt], 0,0,0);
                acc2[nt] = __builtin_amdgcn_mfma_f32_16x16x32_bf16(ah, wl, acc2[nt], 0,0,0);
                acc2[nt] = __builtin_amdgcn_mfma_f32_16x16x32_bf16(al, wh, acc2[nt], 0,0,0);
            }
        }
        #pragma unroll
        for (int nt=0;nt<4;nt++){
            const int o = (nbase+nt)*16 + L;
            #pragma unroll
            for (int rr=0;rr<4;rr++){
                const float v = acc2[nt][rr];
                const int s = e0 + m0 + Q*4 + rr;
                y2out[s*128 + o] = (unsigned short)f2bf(v);
                sacc[nt] += v; qacc[nt] += v*v;
            }
        }
    }
    #pragma unroll
    for (int nt=0;nt<4;nt++){
        atomicAdd(&ssum[(nbase+nt)*16+L], sacc[nt]);
        atomicAdd(&ssq [(nbase+nt)*16+L], qacc[nt]);
    }
    __syncthreads();
    if (t < 128){
        const int slot = (blockIdx.x & 7) * 128;
        atomicAdd(&bn2s8[slot + t], ssum[t]);
        atomicAdd(&bn2q8[slot + t], ssq[t]);
    }
}

// ------ combine v3: BN2 finalize folded in (SC2/SH2 from 8 slots). ------
__global__ __launch_bounds__(256) void combine_fast_kernel(const unsigned short* y2, const float* attw,
        const float* bn2s8, const float* bn2q8, fpp g2, fpp b2g,
        float* xcomb, float* msum){
    __shared__ float rs[512];
    __shared__ float sSC2[128], sSH2[128];
    const int t=threadIdx.x, w=t>>6, lane=t&63;
    if (t < 128){
        float as=0.f, aq=0.f;
        for (int k=0;k<8;k++){ as += bn2s8[k*128+t]; aq += bn2q8[k*128+t]; }
        const float mu  = as*(1.0f/262144.0f);
        const float var = fmaxf(aq*(1.0f/262144.0f) - mu*mu, 0.f);
        const float sc  = g2[t] * rsqrtf(var + 1e-5f);
        sSC2[t]=sc; sSH2[t]=b2g[t]-mu*sc;
    }
    __syncthreads();
    const int c0 = lane*2;
    const float s2a=sSC2[c0], h2a=sSH2[c0], s2b=sSC2[c0+1], h2b=sSH2[c0+1];
    const int pt0 = blockIdx.x*16 + w*4;
    const int hsel = lane >> 4;              // = c0>>5, same head for both channels
    float m0=0.f, m1=0.f;
    for (int j=0;j<4;j++){
        const int pt = pt0 + j;
        float acc0=0.f, acc1=0.f;
        for (int k=0;k<K_;k++){
            const int s = pt*K_ + k;
            const unsigned v = *(const unsigned*)&y2[s*128 + c0];
            const float aw = attw[s*4 + hsel];
            const float r0 = fmaxf(fmaf(bf2fu((unsigned short)(v & 0xFFFFu)), s2a, h2a), 0.f);
            const float r1 = fmaxf(fmaf(bf2fu((unsigned short)(v >> 16)),    s2b, h2b), 0.f);
            acc0 = fmaf(r0, aw, acc0);
            acc1 = fmaf(r1, aw, acc1);
        }
        *(float2*)&xcomb[pt*128 + c0] = make_float2(acc0, acc1);
        m0 += acc0; m1 += acc1;
    }
    rs[t]=m0; rs[256+t]=m1; __syncthreads();
    if (t<64){
        const int n = (blockIdx.x*16) >> 11;
        atomicAdd(&msum[n*128+2*t],   rs[t]+rs[t+64]+rs[t+128]+rs[t+192]);
        atomicAdd(&msum[n*128+2*t+1], rs[256+t]+rs[256+t+64]+rs[256+t+128]+rs[256+t+192]);
    }
}

// ------ final v4: SE gate + SC finalize folded in (SCSC/SHSC from 16 slots). ------
__global__ __launch_bounds__(256) void final_kernel(fpp feat, fpp scw, const float* xcomb,
        const float* msum, fpp w1se, fpp w2se,
        const float* scs16, const float* scq16, fpp gs, fpp bs, float* out){
    __shared__ float swc[128*65];
    __shared__ float sf[16*64];
    __shared__ float tl[32];
    __shared__ float sSCSC[128], sSHSC[128];
    const int t = threadIdx.x;
    for (int i=t;i<8192;i+=256) swc[(i>>6)*65+(i&63)] = scw[i];
    const int row0 = blockIdx.x*16;
    const int n = row0 >> 11;                // uniform: 2048 % 16 == 0
    for (int i=t;i<1024;i+=256) sf[i] = feat[row0*64+i];
    if (t < 32){
        float acc=0.f;
        for (int c=0;c<128;c++) acc = fmaf(msum[n*128+c]*(1.f/2048.f), w1se[t*128+c], acc);
        tl[t] = fmaxf(acc, 0.f);
    }
    if (t < 128){
        float as=0.f, aq=0.f;
        for (int k=0;k<16;k++){ as += scs16[k*128+t]; aq += scq16[k*128+t]; }
        const float mu  = as*(1.0f/16384.0f);
        const float var = fmaxf(aq*(1.0f/16384.0f) - mu*mu, 0.f);
        const float sc  = gs[t] * rsqrtf(var + 1e-5f);
        sSCSC[t]=sc; sSHSC[t]=bs[t]-mu*sc;
    }
    __syncthreads();
    const int c = t & 127, rg = t >> 7;
    float acc2 = 0.f;
    for (int hh=0;hh<32;hh++) acc2 = fmaf(tl[hh], w2se[c*32+hh], acc2);
    const float sev = 1.f/(1.f+expf(-acc2));
    const float scl = sSCSC[c], shf = sSHSC[c];
    for (int r=rg*8; r<rg*8+8; r++){
        const int row = row0 + r;
        float acc = 0.f;
        #pragma unroll
        for (int k=0;k<64;k++) acc = fmaf(sf[r*64+k], swc[c*65+k], acc);
        out[row*128+c] = xcomb[row*128+c]*sev + fmaxf(fmaf(acc, scl, shf), 0.f);
    }
}

extern "C" void kernel_launch(void* const* d_in, const int* in_sizes, int n_in,
                              void* d_out, int out_size, void* d_ws, size_t ws_size,
                              hipStream_t stream) {
    fpp points  = (fpp)d_in[0];
    fpp feat    = (fpp)d_in[1];
    fpp conv_w0 = (fpp)d_in[2];
    fpp conv_w1 = (fpp)d_in[3];
    fpp conv_w2 = (fpp)d_in[4];
    fpp bn_g0 = (fpp)d_in[5],  bn_b0 = (fpp)d_in[6];
    fpp bn_g1 = (fpp)d_in[7],  bn_b1 = (fpp)d_in[8];
    fpp bn_g2 = (fpp)d_in[9],  bn_b2 = (fpp)d_in[10];
    fpp attn_w1 = (fpp)d_in[11], attn_b1 = (fpp)d_in[12];
    fpp attn_w2 = (fpp)d_in[13], attn_b2 = (fpp)d_in[14];
    fpp tau  = (fpp)d_in[15];
    fpp sc_w = (fpp)d_in[16], sc_g = (fpp)d_in[17], sc_b = (fpp)d_in[18];
    fpp se_w1 = (fpp)d_in[19], se_w2 = (fpp)d_in[20];

    float* W = (float*)d_ws;
    float* MSUM=W+1536;
    // slotted atomic stat arrays (all inside first 16384-float memset):
    float* BN0S32=W+4096;  float* BN0Q32=W+6144;    // 32 x 64
    float* BN1S8 =W+8192;  float* BN1Q8 =W+8704;    // 8 x 64
    float* BN2S8 =W+9216;  float* BN2Q8 =W+10240;   // 8 x 128
    float* SCS16 =W+11264; float* SCQ16 =W+13312;   // 16 x 128
    int*   IDX  = (int*)(W + 16384);                 // 262144 ints -> ends 278528
    float* U    = W + 278528;
    float* V    = U + 1048576;
    float* AU   = V + 1048576;
    float* AV   = AU + 524288;
    float* ATTW = AV + 524288;
    float* XCOMB= ATTW + 1048576;                    // 2097152 floats -> ends 6569984
    unsigned short* Y2 = (unsigned short*)(W + 6569984);   // 33,554,432 ushort
    unsigned short* Y1 = Y2 + 33554432;                    // 16,777,216 ushort
    // PTS4 aliases XCOMB (knn finishes long before combine writes XCOMB)
    float4* PTS4 = (float4*)XCOMB;                   // 16384 float4 = 256 KB

    hipMemsetAsync(d_ws, 0, 16384*sizeof(float), stream);

    pts_prep_kernel<<<64, 256, 0, stream>>>(points, PTS4);
    knn_kernel<<<2048, 256, 0, stream>>>(PTS4, IDX);
    feat_gemm_kernel<<<1024, 320, 0, stream>>>(feat, conv_w0, attn_w1, sc_w,
                                               U, V, AU, AV, SCS16, SCQ16);
    attn_bn0_kernel<<<2048, 256, 0, stream>>>(IDX, U, V, AU, AV,
                                              attn_b1, attn_w2, attn_b2, tau,
                                              ATTW, BN0S32, BN0Q32);
    mfma_conv1_kernel<<<512, 512, 0, stream>>>(IDX, U, V, conv_w1,
                                               BN0S32, BN0Q32, bn_g0, bn_b0,
                                               BN1S8, BN1Q8, Y1);
    mfma_conv2_kernel<<<512, 512, 0, stream>>>(Y1, conv_w2,
                                               BN1S8, BN1Q8, bn_g1, bn_b1,
                                               BN2S8, BN2Q8, Y2);
    combine_fast_kernel<<<1024, 256, 0, stream>>>(Y2, ATTW,
                                                  BN2S8, BN2Q8, bn_g2, bn_b2,
                                                  XCOMB, MSUM);
    final_kernel<<<1024, 256, 0, stream>>>(feat, sc_w, XCOMB, MSUM, se_w1, se_w2,
                                           SCS16, SCQ16, sc_g, sc_b, (float*)d_out);
}